// Round 5
// baseline (776.616 us; speedup 1.0000x reference)
//
#include <hip/hip_runtime.h>
#include <hip/hip_bf16.h>
#include <math.h>

#define BB 4
#define HH 56
#define WW 56
#define DM 96
#define DI 192
#define NS 16
#define RK 6
#define KG 4
#define LL (HH*WW)          // 3136
#define NPIX (BB*LL)        // 12544
#define CHL 64              // scan chunk length
#define NCH (LL/CHL)        // 49 chunks
#define NDT (DI/16)         // 12
#define XP 32               // xproj pixels per block
#define NC 38               // RK + 2*NS
#define PAD 196             // padded row length

// pixel index (row-major) feeding/receiving scan position l of direction k
static __device__ __forceinline__ int qmap(int k, int l){
    int m = (k & 2) ? (LL - 1 - l) : l;
    if (k & 1) { int w = m / HH; int h = m % HH; return h * WW + w; }
    return m;
}

static __device__ __forceinline__ float silu(float x){ return x / (1.f + __expf(-x)); }

// ---------------- Stage 1: in_proj (384x96 matvec per pixel), 4 px/block ----
__global__ __launch_bounds__(384) void k_inproj(const float* __restrict__ x,
        const float* __restrict__ Win,
        float* __restrict__ conv_in, float* __restrict__ z_silu)
{
    __shared__ float sx[4*DM];
    int pb  = blockIdx.x * 4;
    int tid = threadIdx.x;
    sx[tid] = x[(size_t)pb*DM + tid];
    __syncthreads();
    float a0=0.f, a1=0.f, a2=0.f, a3=0.f;
    const float* wr = Win + (size_t)tid*DM;
    #pragma unroll 4
    for (int i = 0; i < DM; ++i){
        float w = wr[i];
        a0 = fmaf(sx[i],        w, a0);
        a1 = fmaf(sx[DM+i],     w, a1);
        a2 = fmaf(sx[2*DM+i],   w, a2);
        a3 = fmaf(sx[3*DM+i],   w, a3);
    }
    if (tid < DI){
        conv_in[(size_t)(pb+0)*DI + tid] = a0;
        conv_in[(size_t)(pb+1)*DI + tid] = a1;
        conv_in[(size_t)(pb+2)*DI + tid] = a2;
        conv_in[(size_t)(pb+3)*DI + tid] = a3;
    } else {
        int d = tid - DI;
        z_silu[(size_t)(pb+0)*DI + d] = silu(a0);
        z_silu[(size_t)(pb+1)*DI + d] = silu(a1);
        z_silu[(size_t)(pb+2)*DI + d] = silu(a2);
        z_silu[(size_t)(pb+3)*DI + d] = silu(a3);
    }
}

// ---------------- Stage 2: depthwise 3x3 conv + bias + silu ------------------
__global__ __launch_bounds__(256) void k_conv(const float* __restrict__ conv_in,
    const float* __restrict__ cw, const float* __restrict__ cb,
    float* __restrict__ xc)
{
    int idx = blockIdx.x*256 + threadIdx.x;
    int d = idx % DI;
    int p = (idx / DI) % LL;
    int b = idx / (DI*LL);
    int h = p / WW, w = p % WW;
    float acc = cb[d];
    #pragma unroll
    for (int dy = -1; dy <= 1; ++dy){
        int hy = h + dy; if (hy < 0 || hy >= HH) continue;
        #pragma unroll
        for (int dx = -1; dx <= 1; ++dx){
            int wx = w + dx; if (wx < 0 || wx >= WW) continue;
            acc = fmaf(conv_in[((size_t)b*LL + hy*WW + wx)*DI + d],
                       cw[d*9 + (dy+1)*3 + (dx+1)], acc);
        }
    }
    xc[idx] = silu(acc);
}

// ---------------- Stage 3: x_proj as LDS-tiled GEMM (M=32,N=38,K=192) --------
__global__ __launch_bounds__(256) void k_xproj(const float* __restrict__ xc,
   const float* __restrict__ xpw, const float* __restrict__ dtw,
   const float* __restrict__ dtb,
   float* __restrict__ delta, float* __restrict__ Bsb, float* __restrict__ Csb)
{
    __shared__ float sw[NC*PAD];
    __shared__ float su[XP*PAD];
    __shared__ float sxd[XP][40];
    __shared__ float sdtw[DI*RK];
    int gb = blockIdx.x;
    int bk = gb / (LL/XP); int l0 = (gb % (LL/XP)) * XP;
    int b = bk >> 2, k = bk & 3;
    int tid = threadIdx.x;

    for (int t = tid; t < NC*48; t += 256){
        int c = t / 48, i4 = t % 48;
        float4 w = ((const float4*)(xpw + ((size_t)k*NC + c)*DI))[i4];
        *((float4*)&sw[c*PAD + i4*4]) = w;
    }
    for (int t = tid; t < XP*48; t += 256){
        int lo = t / 48, i4 = t % 48;
        int p = qmap(k, l0 + lo);
        float4 u = ((const float4*)(xc + ((size_t)b*LL + p)*DI))[i4];
        *((float4*)&su[lo*PAD + i4*4]) = u;
    }
    for (int t = tid; t < DI*RK; t += 256) sdtw[t] = dtw[(size_t)k*DI*RK + t];
    __syncthreads();

    for (int q = tid; q < 19*16; q += 256){
        int c2 = q >> 4, lo = q & 15;
        int c0 = 2*c2, c1 = c0 + 1;
        const float4* wa = (const float4*)&sw[c0*PAD];
        const float4* wb = (const float4*)&sw[c1*PAD];
        const float4* ua = (const float4*)&su[lo*PAD];
        const float4* ub = (const float4*)&su[(lo+16)*PAD];
        float a00=0.f, a01=0.f, a10=0.f, a11=0.f;
        #pragma unroll 4
        for (int i4 = 0; i4 < 48; ++i4){
            float4 w0 = wa[i4], w1 = wb[i4], u0 = ua[i4], u1 = ub[i4];
            a00 = fmaf(u0.x,w0.x,a00); a00 = fmaf(u0.y,w0.y,a00);
            a00 = fmaf(u0.z,w0.z,a00); a00 = fmaf(u0.w,w0.w,a00);
            a01 = fmaf(u0.x,w1.x,a01); a01 = fmaf(u0.y,w1.y,a01);
            a01 = fmaf(u0.z,w1.z,a01); a01 = fmaf(u0.w,w1.w,a01);
            a10 = fmaf(u1.x,w0.x,a10); a10 = fmaf(u1.y,w0.y,a10);
            a10 = fmaf(u1.z,w0.z,a10); a10 = fmaf(u1.w,w0.w,a10);
            a11 = fmaf(u1.x,w1.x,a11); a11 = fmaf(u1.y,w1.y,a11);
            a11 = fmaf(u1.z,w1.z,a11); a11 = fmaf(u1.w,w1.w,a11);
        }
        sxd[lo][c0] = a00; sxd[lo][c1] = a01;
        sxd[lo+16][c0] = a10; sxd[lo+16][c1] = a11;
    }
    __syncthreads();

    for (int e = tid; e < XP*DI; e += 256){
        int lo = e / DI, d = e % DI;
        float a = dtb[k*DI + d];
        #pragma unroll
        for (int r = 0; r < RK; ++r) a = fmaf(sxd[lo][r], sdtw[d*RK + r], a);
        float sp = (a > 20.f) ? a : log1pf(__expf(a));
        delta[((size_t)bk*LL + l0+lo)*DI + d] = sp;
    }
    for (int t = tid; t < XP*NS; t += 256){
        int lo = t / NS, n = t % NS;
        Bsb[((size_t)bk*LL + l0+lo)*NS + n] = sxd[lo][RK + n];
        Csb[((size_t)bk*LL + l0+lo)*NS + n] = sxd[lo][RK + NS + n];
    }
}

// ---------------- Stage 5 P1: local chunk recurrence, h[16] in registers -----
// grid: bk(16) x ch(49) = 784; block 192 threads (one per d). No shuffles.
__global__ __launch_bounds__(192) void k_scan1(const float* __restrict__ delta,
    const float* __restrict__ xc, const float* __restrict__ Bsb,
    const float* __restrict__ Alog,
    float* __restrict__ hend, float* __restrict__ sumdl)
{
    __shared__ float sB[CHL][NS];
    int bid = blockIdx.x;
    int bk = bid / NCH, ch = bid % NCH;
    int b = bk >> 2, k = bk & 3;
    int d = threadIdx.x;
    int l0 = ch*CHL;

    const float* dbase = delta + ((size_t)bk*LL + l0)*DI + d;
    const float* xbase = xc + (size_t)b*LL*DI + d;
    const float* Bb = Bsb + ((size_t)bk*LL + l0)*NS;
    for (int t = d; t < CHL*NS; t += 192) ((float*)sB)[t] = Bb[t];

    float An[NS];
    {
        const float* ab = Alog + ((size_t)k*DI + d)*NS;
        #pragma unroll
        for (int n = 0; n < NS; ++n) An[n] = -__expf(ab[n]);
    }
    __syncthreads();

    float h[NS];
    #pragma unroll
    for (int n = 0; n < NS; ++n) h[n] = 0.f;
    float S = 0.f;

    float pdl[2][8], pu[2][8];
    #pragma unroll
    for (int j = 0; j < 8; ++j){
        pdl[0][j] = dbase[(size_t)j*DI];
        pu [0][j] = xbase[(size_t)qmap(k, l0+j)*DI];
    }
    #pragma unroll
    for (int t = 0; t < 8; ++t){
        const int cur = t & 1, nxt = cur ^ 1;
        if (t < 7){
            int lb = (t+1)*8;
            #pragma unroll
            for (int j = 0; j < 8; ++j){
                pdl[nxt][j] = dbase[(size_t)(lb+j)*DI];
                pu [nxt][j] = xbase[(size_t)qmap(k, l0+lb+j)*DI];
            }
        }
        #pragma unroll
        for (int j = 0; j < 8; ++j){
            int l = t*8 + j;
            float dl = pdl[cur][j], uu = pu[cur][j];
            S += dl;
            float dlu = dl * uu;
            const float4* br = (const float4*)&sB[l][0];
            float4 b0 = br[0], b1 = br[1], b2 = br[2], b3 = br[3];
            float bv[NS] = {b0.x,b0.y,b0.z,b0.w, b1.x,b1.y,b1.z,b1.w,
                            b2.x,b2.y,b2.z,b2.w, b3.x,b3.y,b3.z,b3.w};
            #pragma unroll
            for (int n = 0; n < NS; ++n)
                h[n] = fmaf(__expf(dl*An[n]), h[n], dlu*bv[n]);
        }
    }
    size_t hb = ((size_t)bk*NCH + ch)*NS*DI + d;
    #pragma unroll
    for (int n = 0; n < NS; ++n) hend[hb + (size_t)n*DI] = h[n];
    sumdl[((size_t)bk*NCH + ch)*DI + d] = S;
}

// ---------------- Stage 5 P2: combine chunk states in-place (hend -> H0) -----
// grid: 16 bk x 12 part; block 256 = 16 dsub x 16 n
__global__ __launch_bounds__(256) void k_scan2(float* __restrict__ hend,
    const float* __restrict__ sumdl, const float* __restrict__ Alog)
{
    int blk = blockIdx.x;
    int bk = blk / NDT, part = blk % NDT;
    int k = bk & 3;
    int tid = threadIdx.x;
    int dsub = tid & 15, n = tid >> 4;
    int d = part*16 + dsub;
    float An = -__expf(Alog[((size_t)k*DI + d)*NS + n]);
    size_t base  = ((size_t)bk*NCH)*NS*DI + (size_t)n*DI + d;
    size_t sbase = (size_t)bk*NCH*DI + d;
    float H = 0.f;
    float he = hend[base], S = sumdl[sbase];
    for (int c = 0; c < NCH; ++c){
        float heN = 0.f, SN = 0.f;
        if (c+1 < NCH){
            heN = hend [base  + (size_t)(c+1)*NS*DI];
            SN  = sumdl[sbase + (size_t)(c+1)*DI];
        }
        hend[base + (size_t)c*NS*DI] = H;   // overwrite with H0 (state before chunk c)
        H  = fmaf(__expf(An*S), H, he);
        he = heN; S = SN;
    }
}

// ---------------- Stage 5 P3: full recurrence from H0, emit y ---------------
// grid: bk(16) x ch(49); block 192 (one per d). One coalesced atomic row/step.
__global__ __launch_bounds__(192) void k_scan3(const float* __restrict__ delta,
    const float* __restrict__ xc, const float* __restrict__ Bsb,
    const float* __restrict__ Csb, const float* __restrict__ Alog,
    const float* __restrict__ Dsv, const float* __restrict__ H0,
    float* __restrict__ y_acc)
{
    __shared__ float sB[CHL][NS], sC[CHL][NS];
    int bid = blockIdx.x;
    int bk = bid / NCH, ch = bid % NCH;
    int b = bk >> 2, k = bk & 3;
    int d = threadIdx.x;
    int l0 = ch*CHL;

    const float* dbase = delta + ((size_t)bk*LL + l0)*DI + d;
    const float* xbase = xc + (size_t)b*LL*DI + d;
    const float* Bb = Bsb + ((size_t)bk*LL + l0)*NS;
    const float* Cb = Csb + ((size_t)bk*LL + l0)*NS;
    float* ybase = y_acc + (size_t)b*LL*DI + d;
    for (int t = d; t < CHL*NS; t += 192){
        ((float*)sB)[t] = Bb[t];
        ((float*)sC)[t] = Cb[t];
    }

    float An[NS];
    {
        const float* ab = Alog + ((size_t)k*DI + d)*NS;
        #pragma unroll
        for (int n = 0; n < NS; ++n) An[n] = -__expf(ab[n]);
    }
    float Dv = Dsv[k*DI + d];

    float h[NS];
    size_t hb = ((size_t)bk*NCH + ch)*NS*DI + d;
    #pragma unroll
    for (int n = 0; n < NS; ++n) h[n] = H0[hb + (size_t)n*DI];
    __syncthreads();

    float pdl[2][8], pu[2][8];
    #pragma unroll
    for (int j = 0; j < 8; ++j){
        pdl[0][j] = dbase[(size_t)j*DI];
        pu [0][j] = xbase[(size_t)qmap(k, l0+j)*DI];
    }
    #pragma unroll
    for (int t = 0; t < 8; ++t){
        const int cur = t & 1, nxt = cur ^ 1;
        if (t < 7){
            int lb = (t+1)*8;
            #pragma unroll
            for (int j = 0; j < 8; ++j){
                pdl[nxt][j] = dbase[(size_t)(lb+j)*DI];
                pu [nxt][j] = xbase[(size_t)qmap(k, l0+lb+j)*DI];
            }
        }
        #pragma unroll
        for (int j = 0; j < 8; ++j){
            int l = t*8 + j;
            float dl = pdl[cur][j], uu = pu[cur][j];
            float dlu = dl * uu;
            const float4* br = (const float4*)&sB[l][0];
            const float4* cr = (const float4*)&sC[l][0];
            float4 b0 = br[0], b1 = br[1], b2 = br[2], b3 = br[3];
            float4 c0 = cr[0], c1 = cr[1], c2 = cr[2], c3 = cr[3];
            float bv[NS] = {b0.x,b0.y,b0.z,b0.w, b1.x,b1.y,b1.z,b1.w,
                            b2.x,b2.y,b2.z,b2.w, b3.x,b3.y,b3.z,b3.w};
            float cv[NS] = {c0.x,c0.y,c0.z,c0.w, c1.x,c1.y,c1.z,c1.w,
                            c2.x,c2.y,c2.z,c2.w, c3.x,c3.y,c3.z,c3.w};
            #pragma unroll
            for (int n = 0; n < NS; ++n)
                h[n] = fmaf(__expf(dl*An[n]), h[n], dlu*bv[n]);
            float y0=0.f, y1=0.f, y2=0.f, y3=0.f;
            #pragma unroll
            for (int n = 0; n < NS; n += 4){
                y0 = fmaf(h[n+0], cv[n+0], y0);
                y1 = fmaf(h[n+1], cv[n+1], y1);
                y2 = fmaf(h[n+2], cv[n+2], y2);
                y3 = fmaf(h[n+3], cv[n+3], y3);
            }
            float y = ((y0+y1)+(y2+y3)) + uu*Dv;
            atomicAdd(&ybase[(size_t)qmap(k, l0+l)*DI], y);
        }
    }
}

// ---------------- Stage 6: LayerNorm + z-gate + out_proj ---------------------
__global__ __launch_bounds__(192) void k_lnout(const float* __restrict__ y_acc,
    const float* __restrict__ z_silu, const float* __restrict__ lnw,
    const float* __restrict__ lnb, const float* __restrict__ Wout,
    float* __restrict__ out)
{
    __shared__ float syz[DI];
    __shared__ float red[2][3];
    __shared__ float mb[2];
    int pg  = blockIdx.x;
    int tid = threadIdx.x;
    float v = y_acc[(size_t)pg*DI + tid];
    float s = v, sq = v*v;
    #pragma unroll
    for (int m = 32; m >= 1; m >>= 1){ s += __shfl_xor(s, m); sq += __shfl_xor(sq, m); }
    int wid = tid >> 6, lane = tid & 63;
    if (lane == 0){ red[0][wid] = s; red[1][wid] = sq; }
    __syncthreads();
    if (tid == 0){
        float ts = red[0][0] + red[0][1] + red[0][2];
        float tq = red[1][0] + red[1][1] + red[1][2];
        float mu  = ts * (1.f/DI);
        float var = tq * (1.f/DI) - mu*mu;
        mb[0] = mu; mb[1] = rsqrtf(var + 1e-5f);
    }
    __syncthreads();
    float yn = (v - mb[0]) * mb[1] * lnw[tid] + lnb[tid];
    syz[tid] = yn * z_silu[(size_t)pg*DI + tid];
    __syncthreads();
    if (tid < DM){
        const float* wr = Wout + (size_t)tid*DI;
        float acc = 0.f;
        #pragma unroll 4
        for (int i = 0; i < DI; ++i) acc = fmaf(syz[i], wr[i], acc);
        out[(size_t)pg*DM + tid] = acc;
    }
}

extern "C" void kernel_launch(void* const* d_in, const int* in_sizes, int n_in,
                              void* d_out, int out_size, void* d_ws, size_t ws_size,
                              hipStream_t stream)
{
    const float* x    = (const float*)d_in[0];
    const float* Win  = (const float*)d_in[1];
    const float* cw   = (const float*)d_in[2];
    const float* cb   = (const float*)d_in[3];
    const float* xpw  = (const float*)d_in[4];
    const float* dtw  = (const float*)d_in[5];
    const float* dtb  = (const float*)d_in[6];
    const float* Alog = (const float*)d_in[7];
    const float* Dsv  = (const float*)d_in[8];
    const float* lnw  = (const float*)d_in[9];
    const float* lnb  = (const float*)d_in[10];
    const float* Wout = (const float*)d_in[11];
    float* out = (float*)d_out;

    float* ws      = (float*)d_ws;
    float* conv_in = ws;                                    // [NPIX,DI] dead after k_conv
    float* z_silu  = conv_in + (size_t)NPIX*DI;             // [NPIX,DI]
    float* xc      = z_silu  + (size_t)NPIX*DI;             // [NPIX,DI] live through P3
    float* delta   = xc      + (size_t)NPIX*DI;             // [16,LL,DI]
    float* Bsb     = delta   + (size_t)BB*KG*LL*DI;         // [16,LL,NS]
    float* Csb     = Bsb     + (size_t)BB*KG*LL*NS;         // [16,LL,NS]
    float* sumdl   = Csb     + (size_t)BB*KG*LL*NS;         // [16,49,DI]
    float* y_acc   = sumdl   + (size_t)BB*KG*NCH*DI;        // [NPIX,DI]
    float* hend    = conv_in;  // alias: [16,49,NS,DI] == NPIX*DI exactly; H0 in-place after P2

    hipLaunchKernelGGL(k_inproj, dim3(NPIX/4), dim3(384), 0, stream, x, Win, conv_in, z_silu);
    hipLaunchKernelGGL(k_conv,   dim3((NPIX*DI)/256), dim3(256), 0, stream, conv_in, cw, cb, xc);
    hipLaunchKernelGGL(k_xproj,  dim3(BB*KG*(LL/XP)), dim3(256), 0, stream, xc, xpw, dtw, dtb, delta, Bsb, Csb);
    hipMemsetAsync(y_acc, 0, (size_t)NPIX*DI*sizeof(float), stream);
    hipLaunchKernelGGL(k_scan1, dim3(BB*KG*NCH), dim3(192), 0, stream,
                       delta, xc, Bsb, Alog, hend, sumdl);
    hipLaunchKernelGGL(k_scan2, dim3(BB*KG*NDT), dim3(256), 0, stream,
                       hend, sumdl, Alog);
    hipLaunchKernelGGL(k_scan3, dim3(BB*KG*NCH), dim3(192), 0, stream,
                       delta, xc, Bsb, Csb, Alog, Dsv, hend, y_acc);
    hipLaunchKernelGGL(k_lnout,  dim3(NPIX), dim3(192), 0, stream, y_acc, z_silu, lnw, lnb, Wout, out);
}

// Round 6
// 373.651 us; speedup vs baseline: 2.0784x; 2.0784x over previous
//
#include <hip/hip_runtime.h>
#include <hip/hip_bf16.h>
#include <math.h>

#define BB 4
#define HH 56
#define WW 56
#define DM 96
#define DI 192
#define NS 16
#define RK 6
#define KG 4
#define LL (HH*WW)          // 3136
#define NPIX (BB*LL)        // 12544
#define CHL 64              // scan chunk length
#define NCH (LL/CHL)        // 49 chunks
#define NDT (DI/16)         // 12
#define XP 32               // xproj pixels per block
#define NC 38               // RK + 2*NS
#define PAD 196             // padded row length

static __device__ __forceinline__ int qmap(int k, int l){
    int m = (k & 2) ? (LL - 1 - l) : l;
    if (k & 1) { int w = m / HH; int h = m % HH; return h * WW + w; }
    return m;
}

static __device__ __forceinline__ float silu(float x){ return x / (1.f + __expf(-x)); }

// ---------------- Stage 0: transpose weights (one-time, tiny) ----------------
__global__ __launch_bounds__(256) void k_prep(const float* __restrict__ Win,
    const float* __restrict__ Wout, float* __restrict__ WinT, float* __restrict__ WoutT)
{
    int t = blockIdx.x*256 + threadIdx.x;
    if (t < 384*DM){                 // WinT[i*384+c] = Win[c*96+i]
        int i = t / 384, c = t % 384;
        WinT[t] = Win[(size_t)c*DM + i];
    } else if (t < 384*DM + DI*DM){  // WoutT[i*96+c] = Wout[c*192+i]
        int t2 = t - 384*DM;
        int i = t2 / DM, c = t2 % DM;
        WoutT[t2] = Wout[(size_t)c*DI + i];
    }
}

// ---------------- Stage 1: in_proj, 8 px/block, coalesced WinT ---------------
__global__ __launch_bounds__(384) void k_inproj(const float* __restrict__ x,
        const float* __restrict__ WinT,
        float* __restrict__ conv_in, float* __restrict__ z_silu)
{
    __shared__ float sx[8*DM];
    int pb  = blockIdx.x * 8;
    int c = threadIdx.x;
    sx[c]       = x[(size_t)pb*DM + c];
    sx[c + 384] = x[(size_t)pb*DM + 384 + c];
    __syncthreads();
    float a0=0,a1=0,a2=0,a3=0,a4=0,a5=0,a6=0,a7=0;
    for (int i = 0; i < DM; ++i){
        float w = WinT[(size_t)i*384 + c];          // lane-coalesced
        a0=fmaf(sx[i],w,a0);        a1=fmaf(sx[DM+i],w,a1);
        a2=fmaf(sx[2*DM+i],w,a2);   a3=fmaf(sx[3*DM+i],w,a3);
        a4=fmaf(sx[4*DM+i],w,a4);   a5=fmaf(sx[5*DM+i],w,a5);
        a6=fmaf(sx[6*DM+i],w,a6);   a7=fmaf(sx[7*DM+i],w,a7);
    }
    if (c < DI){
        conv_in[(size_t)(pb+0)*DI+c]=a0; conv_in[(size_t)(pb+1)*DI+c]=a1;
        conv_in[(size_t)(pb+2)*DI+c]=a2; conv_in[(size_t)(pb+3)*DI+c]=a3;
        conv_in[(size_t)(pb+4)*DI+c]=a4; conv_in[(size_t)(pb+5)*DI+c]=a5;
        conv_in[(size_t)(pb+6)*DI+c]=a6; conv_in[(size_t)(pb+7)*DI+c]=a7;
    } else {
        int d = c - DI;
        z_silu[(size_t)(pb+0)*DI+d]=silu(a0); z_silu[(size_t)(pb+1)*DI+d]=silu(a1);
        z_silu[(size_t)(pb+2)*DI+d]=silu(a2); z_silu[(size_t)(pb+3)*DI+d]=silu(a3);
        z_silu[(size_t)(pb+4)*DI+d]=silu(a4); z_silu[(size_t)(pb+5)*DI+d]=silu(a5);
        z_silu[(size_t)(pb+6)*DI+d]=silu(a6); z_silu[(size_t)(pb+7)*DI+d]=silu(a7);
    }
}

// ---------------- Stage 2: depthwise 3x3 conv + bias + silu ------------------
__global__ __launch_bounds__(256) void k_conv(const float* __restrict__ conv_in,
    const float* __restrict__ cw, const float* __restrict__ cb,
    float* __restrict__ xc)
{
    __shared__ float scw[DI*9];
    int tid = threadIdx.x;
    for (int t = tid; t < DI*9; t += 256) scw[t] = cw[t];
    __syncthreads();
    int idx = blockIdx.x*256 + tid;
    int d = idx % DI;
    int p = (idx / DI) % LL;
    int b = idx / (DI*LL);
    int h = p / WW, w = p % WW;
    float acc = cb[d];
    #pragma unroll
    for (int dy = -1; dy <= 1; ++dy){
        int hy = h + dy; if (hy < 0 || hy >= HH) continue;
        #pragma unroll
        for (int dx = -1; dx <= 1; ++dx){
            int wx = w + dx; if (wx < 0 || wx >= WW) continue;
            acc = fmaf(conv_in[((size_t)b*LL + hy*WW + wx)*DI + d],
                       scw[d*9 + (dy+1)*3 + (dx+1)], acc);
        }
    }
    xc[idx] = silu(acc);
}

// ---------------- Stage 3: x_proj as LDS-tiled GEMM (M=32,N=38,K=192) --------
__global__ __launch_bounds__(256) void k_xproj(const float* __restrict__ xc,
   const float* __restrict__ xpw, const float* __restrict__ dtw,
   const float* __restrict__ dtb,
   float* __restrict__ delta, float* __restrict__ Bsb, float* __restrict__ Csb)
{
    __shared__ float sw[NC*PAD];
    __shared__ float su[XP*PAD];
    __shared__ float sxd[XP][40];
    __shared__ float sdtw[DI*RK];
    int gb = blockIdx.x;
    int bk = gb / (LL/XP); int l0 = (gb % (LL/XP)) * XP;
    int b = bk >> 2, k = bk & 3;
    int tid = threadIdx.x;

    for (int t = tid; t < NC*48; t += 256){
        int c = t / 48, i4 = t % 48;
        float4 w = ((const float4*)(xpw + ((size_t)k*NC + c)*DI))[i4];
        *((float4*)&sw[c*PAD + i4*4]) = w;
    }
    for (int t = tid; t < XP*48; t += 256){
        int lo = t / 48, i4 = t % 48;
        int p = qmap(k, l0 + lo);
        float4 u = ((const float4*)(xc + ((size_t)b*LL + p)*DI))[i4];
        *((float4*)&su[lo*PAD + i4*4]) = u;
    }
    for (int t = tid; t < DI*RK; t += 256) sdtw[t] = dtw[(size_t)k*DI*RK + t];
    __syncthreads();

    for (int q = tid; q < 19*16; q += 256){
        int c2 = q >> 4, lo = q & 15;
        int c0 = 2*c2, c1 = c0 + 1;
        const float4* wa = (const float4*)&sw[c0*PAD];
        const float4* wb = (const float4*)&sw[c1*PAD];
        const float4* ua = (const float4*)&su[lo*PAD];
        const float4* ub = (const float4*)&su[(lo+16)*PAD];
        float a00=0.f, a01=0.f, a10=0.f, a11=0.f;
        #pragma unroll 4
        for (int i4 = 0; i4 < 48; ++i4){
            float4 w0 = wa[i4], w1 = wb[i4], u0 = ua[i4], u1 = ub[i4];
            a00 = fmaf(u0.x,w0.x,a00); a00 = fmaf(u0.y,w0.y,a00);
            a00 = fmaf(u0.z,w0.z,a00); a00 = fmaf(u0.w,w0.w,a00);
            a01 = fmaf(u0.x,w1.x,a01); a01 = fmaf(u0.y,w1.y,a01);
            a01 = fmaf(u0.z,w1.z,a01); a01 = fmaf(u0.w,w1.w,a01);
            a10 = fmaf(u1.x,w0.x,a10); a10 = fmaf(u1.y,w0.y,a10);
            a10 = fmaf(u1.z,w0.z,a10); a10 = fmaf(u1.w,w0.w,a10);
            a11 = fmaf(u1.x,w1.x,a11); a11 = fmaf(u1.y,w1.y,a11);
            a11 = fmaf(u1.z,w1.z,a11); a11 = fmaf(u1.w,w1.w,a11);
        }
        sxd[lo][c0] = a00; sxd[lo][c1] = a01;
        sxd[lo+16][c0] = a10; sxd[lo+16][c1] = a11;
    }
    __syncthreads();

    for (int e = tid; e < XP*DI; e += 256){
        int lo = e / DI, d = e % DI;
        float a = dtb[k*DI + d];
        #pragma unroll
        for (int r = 0; r < RK; ++r) a = fmaf(sxd[lo][r], sdtw[d*RK + r], a);
        float sp = (a > 20.f) ? a : log1pf(__expf(a));
        delta[((size_t)bk*LL + l0+lo)*DI + d] = sp;
    }
    for (int t = tid; t < XP*NS; t += 256){
        int lo = t / NS, n = t % NS;
        Bsb[((size_t)bk*LL + l0+lo)*NS + n] = sxd[lo][RK + n];
        Csb[((size_t)bk*LL + l0+lo)*NS + n] = sxd[lo][RK + NS + n];
    }
}

#define HSTEP(i, comp) h[i] = fmaf(__expf(dl*An[i]), h[i], dlu*(comp))
#define YSTEP(i, comp) y = fmaf(h[i], (comp), y)

// ---------------- Stage 5 P1: local chunk recurrence, h[16] in registers -----
// grid: bk(16) x ch(49); block 192 (one per d). unroll-1 loop, 1-deep prefetch.
__global__ __launch_bounds__(192, 4) void k_scan1(const float* __restrict__ delta,
    const float* __restrict__ xc, const float* __restrict__ Bsb,
    const float* __restrict__ Alog,
    float* __restrict__ hend, float* __restrict__ sumdl)
{
    __shared__ float sB[CHL][NS];
    int bid = blockIdx.x;
    int bk = bid / NCH, ch = bid % NCH;
    int b = bk >> 2, k = bk & 3;
    int d = threadIdx.x;
    int l0 = ch*CHL;

    const float* dbase = delta + ((size_t)bk*LL + l0)*DI + d;
    const float* xbase = xc + (size_t)b*LL*DI + d;
    const float* Bb = Bsb + ((size_t)bk*LL + l0)*NS;
    for (int t = d; t < CHL*NS; t += 192) ((float*)sB)[t] = Bb[t];

    float An[NS];
    {
        const float* ab = Alog + ((size_t)k*DI + d)*NS;
        #pragma unroll
        for (int n = 0; n < NS; ++n) An[n] = -__expf(ab[n]);
    }
    __syncthreads();

    float h[NS];
    #pragma unroll
    for (int n = 0; n < NS; ++n) h[n] = 0.f;
    float S = 0.f;

    float dl_n = dbase[0];
    float uu_n = xbase[(size_t)qmap(k, l0)*DI];
    #pragma unroll 1
    for (int l = 0; l < CHL; ++l){
        float dl = dl_n, uu = uu_n;
        if (l + 1 < CHL){
            dl_n = dbase[(size_t)(l+1)*DI];
            uu_n = xbase[(size_t)qmap(k, l0+l+1)*DI];
        }
        S += dl;
        float dlu = dl * uu;
        const float4* br = (const float4*)&sB[l][0];
        float4 b0 = br[0], b1 = br[1], b2 = br[2], b3 = br[3];
        HSTEP(0,b0.x);  HSTEP(1,b0.y);  HSTEP(2,b0.z);  HSTEP(3,b0.w);
        HSTEP(4,b1.x);  HSTEP(5,b1.y);  HSTEP(6,b1.z);  HSTEP(7,b1.w);
        HSTEP(8,b2.x);  HSTEP(9,b2.y);  HSTEP(10,b2.z); HSTEP(11,b2.w);
        HSTEP(12,b3.x); HSTEP(13,b3.y); HSTEP(14,b3.z); HSTEP(15,b3.w);
    }
    size_t hb = ((size_t)bk*NCH + ch)*NS*DI + d;
    #pragma unroll
    for (int n = 0; n < NS; ++n) hend[hb + (size_t)n*DI] = h[n];
    sumdl[((size_t)bk*NCH + ch)*DI + d] = S;
}

// ---------------- Stage 5 P2: combine chunk states in-place (hend -> H0) -----
__global__ __launch_bounds__(256) void k_scan2(float* __restrict__ hend,
    const float* __restrict__ sumdl, const float* __restrict__ Alog)
{
    int blk = blockIdx.x;
    int bk = blk / NDT, part = blk % NDT;
    int k = bk & 3;
    int tid = threadIdx.x;
    int dsub = tid & 15, n = tid >> 4;
    int d = part*16 + dsub;
    float An = -__expf(Alog[((size_t)k*DI + d)*NS + n]);
    size_t base  = ((size_t)bk*NCH)*NS*DI + (size_t)n*DI + d;
    size_t sbase = (size_t)bk*NCH*DI + d;
    float H = 0.f;
    float he = hend[base], S = sumdl[sbase];
    for (int c = 0; c < NCH; ++c){
        float heN = 0.f, SN = 0.f;
        if (c+1 < NCH){
            heN = hend [base  + (size_t)(c+1)*NS*DI];
            SN  = sumdl[sbase + (size_t)(c+1)*DI];
        }
        hend[base + (size_t)c*NS*DI] = H;
        H  = fmaf(__expf(An*S), H, he);
        he = heN; S = SN;
    }
}

// ---------------- Stage 5 P3: full recurrence from H0, emit y ---------------
__global__ __launch_bounds__(192, 4) void k_scan3(const float* __restrict__ delta,
    const float* __restrict__ xc, const float* __restrict__ Bsb,
    const float* __restrict__ Csb, const float* __restrict__ Alog,
    const float* __restrict__ Dsv, const float* __restrict__ H0,
    float* __restrict__ y_acc)
{
    __shared__ float sB[CHL][NS], sC[CHL][NS];
    int bid = blockIdx.x;
    int bk = bid / NCH, ch = bid % NCH;
    int b = bk >> 2, k = bk & 3;
    int d = threadIdx.x;
    int l0 = ch*CHL;

    const float* dbase = delta + ((size_t)bk*LL + l0)*DI + d;
    const float* xbase = xc + (size_t)b*LL*DI + d;
    const float* Bb = Bsb + ((size_t)bk*LL + l0)*NS;
    const float* Cb = Csb + ((size_t)bk*LL + l0)*NS;
    float* ybase = y_acc + (size_t)b*LL*DI + d;
    for (int t = d; t < CHL*NS; t += 192){
        ((float*)sB)[t] = Bb[t];
        ((float*)sC)[t] = Cb[t];
    }

    float An[NS];
    {
        const float* ab = Alog + ((size_t)k*DI + d)*NS;
        #pragma unroll
        for (int n = 0; n < NS; ++n) An[n] = -__expf(ab[n]);
    }
    float Dv = Dsv[k*DI + d];

    float h[NS];
    size_t hb = ((size_t)bk*NCH + ch)*NS*DI + d;
    #pragma unroll
    for (int n = 0; n < NS; ++n) h[n] = H0[hb + (size_t)n*DI];
    __syncthreads();

    int   q_n  = qmap(k, l0);
    float dl_n = dbase[0];
    float uu_n = xbase[(size_t)q_n*DI];
    #pragma unroll 1
    for (int l = 0; l < CHL; ++l){
        float dl = dl_n, uu = uu_n;
        int q = q_n;
        if (l + 1 < CHL){
            q_n  = qmap(k, l0+l+1);
            dl_n = dbase[(size_t)(l+1)*DI];
            uu_n = xbase[(size_t)q_n*DI];
        }
        float dlu = dl * uu;
        const float4* br = (const float4*)&sB[l][0];
        const float4* cr = (const float4*)&sC[l][0];
        float4 b0 = br[0], b1 = br[1], b2 = br[2], b3 = br[3];
        HSTEP(0,b0.x);  HSTEP(1,b0.y);  HSTEP(2,b0.z);  HSTEP(3,b0.w);
        HSTEP(4,b1.x);  HSTEP(5,b1.y);  HSTEP(6,b1.z);  HSTEP(7,b1.w);
        HSTEP(8,b2.x);  HSTEP(9,b2.y);  HSTEP(10,b2.z); HSTEP(11,b2.w);
        HSTEP(12,b3.x); HSTEP(13,b3.y); HSTEP(14,b3.z); HSTEP(15,b3.w);
        float4 c0 = cr[0], c1 = cr[1], c2 = cr[2], c3 = cr[3];
        float y = uu * Dv;
        YSTEP(0,c0.x);  YSTEP(1,c0.y);  YSTEP(2,c0.z);  YSTEP(3,c0.w);
        YSTEP(4,c1.x);  YSTEP(5,c1.y);  YSTEP(6,c1.z);  YSTEP(7,c1.w);
        YSTEP(8,c2.x);  YSTEP(9,c2.y);  YSTEP(10,c2.z); YSTEP(11,c2.w);
        YSTEP(12,c3.x); YSTEP(13,c3.y); YSTEP(14,c3.z); YSTEP(15,c3.w);
        atomicAdd(&ybase[(size_t)q*DI], y);
    }
}

// ---------------- Stage 6: LayerNorm + z-gate + out_proj (split-K) -----------
__global__ __launch_bounds__(192) void k_lnout(const float* __restrict__ y_acc,
    const float* __restrict__ z_silu, const float* __restrict__ lnw,
    const float* __restrict__ lnb, const float* __restrict__ WoutT,
    float* __restrict__ out)
{
    __shared__ float syz[DI];
    __shared__ float red[2][3];
    __shared__ float mb[2];
    __shared__ float sOut[DM];
    int pg  = blockIdx.x;
    int tid = threadIdx.x;
    float v = y_acc[(size_t)pg*DI + tid];
    float s = v, sq = v*v;
    #pragma unroll
    for (int m = 32; m >= 1; m >>= 1){ s += __shfl_xor(s, m); sq += __shfl_xor(sq, m); }
    int wid = tid >> 6, lane = tid & 63;
    if (lane == 0){ red[0][wid] = s; red[1][wid] = sq; }
    __syncthreads();
    if (tid == 0){
        float ts = red[0][0] + red[0][1] + red[0][2];
        float tq = red[1][0] + red[1][1] + red[1][2];
        float mu  = ts * (1.f/DI);
        float var = tq * (1.f/DI) - mu*mu;
        mb[0] = mu; mb[1] = rsqrtf(var + 1e-5f);
    }
    __syncthreads();
    float yn = (v - mb[0]) * mb[1] * lnw[tid] + lnb[tid];
    syz[tid] = yn * z_silu[(size_t)pg*DI + tid];
    __syncthreads();
    int c    = (tid < DM) ? tid : tid - DM;
    int half = (tid >= DM);
    const float* wt = WoutT + (size_t)half*DM*DM + c;   // rows i=half*96..+96
    const float* sv = syz + half*DM;
    float acc = 0.f;
    #pragma unroll 4
    for (int i = 0; i < DM; ++i) acc = fmaf(sv[i], wt[(size_t)i*DM], acc);
    if (half) sOut[c] = acc;
    __syncthreads();
    if (!half) out[(size_t)pg*DM + c] = acc + sOut[c];
}

extern "C" void kernel_launch(void* const* d_in, const int* in_sizes, int n_in,
                              void* d_out, int out_size, void* d_ws, size_t ws_size,
                              hipStream_t stream)
{
    const float* x    = (const float*)d_in[0];
    const float* Win  = (const float*)d_in[1];
    const float* cw   = (const float*)d_in[2];
    const float* cb   = (const float*)d_in[3];
    const float* xpw  = (const float*)d_in[4];
    const float* dtw  = (const float*)d_in[5];
    const float* dtb  = (const float*)d_in[6];
    const float* Alog = (const float*)d_in[7];
    const float* Dsv  = (const float*)d_in[8];
    const float* lnw  = (const float*)d_in[9];
    const float* lnb  = (const float*)d_in[10];
    const float* Wout = (const float*)d_in[11];
    float* out = (float*)d_out;

    float* ws      = (float*)d_ws;
    float* conv_in = ws;                                    // [NPIX,DI] dead after k_conv
    float* z_silu  = conv_in + (size_t)NPIX*DI;             // [NPIX,DI]
    float* xc      = z_silu  + (size_t)NPIX*DI;             // [NPIX,DI] live through P3
    float* delta   = xc      + (size_t)NPIX*DI;             // [16,LL,DI]
    float* Bsb     = delta   + (size_t)BB*KG*LL*DI;         // [16,LL,NS]
    float* Csb     = Bsb     + (size_t)BB*KG*LL*NS;         // [16,LL,NS]
    float* sumdl   = Csb     + (size_t)BB*KG*LL*NS;         // [16,49,DI]
    float* y_acc   = sumdl   + (size_t)BB*KG*NCH*DI;        // [NPIX,DI]
    float* WinT    = y_acc   + (size_t)NPIX*DI;             // [96,384]
    float* WoutT   = WinT    + (size_t)DM*2*DI;             // [192,96]
    float* hend    = conv_in;  // alias: [16,49,NS,DI] == NPIX*DI; H0 in-place after P2

    hipLaunchKernelGGL(k_prep,   dim3((384*DM + DI*DM + 255)/256), dim3(256), 0, stream,
                       Win, Wout, WinT, WoutT);
    hipLaunchKernelGGL(k_inproj, dim3(NPIX/8), dim3(384), 0, stream, x, WinT, conv_in, z_silu);
    hipLaunchKernelGGL(k_conv,   dim3((NPIX*DI)/256), dim3(256), 0, stream, conv_in, cw, cb, xc);
    hipLaunchKernelGGL(k_xproj,  dim3(BB*KG*(LL/XP)), dim3(256), 0, stream, xc, xpw, dtw, dtb, delta, Bsb, Csb);
    hipMemsetAsync(y_acc, 0, (size_t)NPIX*DI*sizeof(float), stream);
    hipLaunchKernelGGL(k_scan1, dim3(BB*KG*NCH), dim3(192), 0, stream,
                       delta, xc, Bsb, Alog, hend, sumdl);
    hipLaunchKernelGGL(k_scan2, dim3(BB*KG*NDT), dim3(256), 0, stream,
                       hend, sumdl, Alog);
    hipLaunchKernelGGL(k_scan3, dim3(BB*KG*NCH), dim3(192), 0, stream,
                       delta, xc, Bsb, Csb, Alog, Dsv, hend, y_acc);
    hipLaunchKernelGGL(k_lnout,  dim3(NPIX), dim3(192), 0, stream, y_acc, z_silu, lnw, lnb, WoutT, out);
}

// Round 7
// 367.930 us; speedup vs baseline: 2.1108x; 1.0155x over previous
//
#include <hip/hip_runtime.h>
#include <hip/hip_bf16.h>
#include <math.h>

#define BB 4
#define HH 56
#define WW 56
#define DM 96
#define DI 192
#define NS 16
#define RK 6
#define KG 4
#define LL (HH*WW)          // 3136
#define NPIX (BB*LL)        // 12544
#define CHL 64              // scan chunk length
#define NCH (LL/CHL)        // 49 chunks
#define NDT (DI/16)         // 12
#define XP 32               // xproj pixels per block
#define NC 38               // RK + 2*NS
#define PAD 196             // padded row length
#define LNPX 8              // lnout pixels per block

static __device__ __forceinline__ int qmap(int k, int l){
    int m = (k & 2) ? (LL - 1 - l) : l;
    if (k & 1) { int w = m / HH; int h = m % HH; return h * WW + w; }
    return m;
}

static __device__ __forceinline__ float silu(float x){ return x / (1.f + __expf(-x)); }

// ---------------- Stage 0: transpose weights (one-time, tiny) ----------------
__global__ __launch_bounds__(256) void k_prep(const float* __restrict__ Win,
    const float* __restrict__ Wout, float* __restrict__ WinT, float* __restrict__ WoutT)
{
    int t = blockIdx.x*256 + threadIdx.x;
    if (t < 384*DM){                 // WinT[i*384+c] = Win[c*96+i]
        int i = t / 384, c = t % 384;
        WinT[t] = Win[(size_t)c*DM + i];
    } else if (t < 384*DM + DI*DM){  // WoutT[i*96+c] = Wout[c*192+i]
        int t2 = t - 384*DM;
        int i = t2 / DM, c = t2 % DM;
        WoutT[t2] = Wout[(size_t)c*DI + i];
    }
}

// ---------------- Stage 1: in_proj, 8 px/block, coalesced WinT ---------------
__global__ __launch_bounds__(384) void k_inproj(const float* __restrict__ x,
        const float* __restrict__ WinT,
        float* __restrict__ conv_in, float* __restrict__ z_silu)
{
    __shared__ float sx[8*DM];
    int pb  = blockIdx.x * 8;
    int c = threadIdx.x;
    sx[c]       = x[(size_t)pb*DM + c];
    sx[c + 384] = x[(size_t)pb*DM + 384 + c];
    __syncthreads();
    float a0=0,a1=0,a2=0,a3=0,a4=0,a5=0,a6=0,a7=0;
    for (int i = 0; i < DM; ++i){
        float w = WinT[(size_t)i*384 + c];          // lane-coalesced
        a0=fmaf(sx[i],w,a0);        a1=fmaf(sx[DM+i],w,a1);
        a2=fmaf(sx[2*DM+i],w,a2);   a3=fmaf(sx[3*DM+i],w,a3);
        a4=fmaf(sx[4*DM+i],w,a4);   a5=fmaf(sx[5*DM+i],w,a5);
        a6=fmaf(sx[6*DM+i],w,a6);   a7=fmaf(sx[7*DM+i],w,a7);
    }
    if (c < DI){
        conv_in[(size_t)(pb+0)*DI+c]=a0; conv_in[(size_t)(pb+1)*DI+c]=a1;
        conv_in[(size_t)(pb+2)*DI+c]=a2; conv_in[(size_t)(pb+3)*DI+c]=a3;
        conv_in[(size_t)(pb+4)*DI+c]=a4; conv_in[(size_t)(pb+5)*DI+c]=a5;
        conv_in[(size_t)(pb+6)*DI+c]=a6; conv_in[(size_t)(pb+7)*DI+c]=a7;
    } else {
        int d = c - DI;
        z_silu[(size_t)(pb+0)*DI+d]=silu(a0); z_silu[(size_t)(pb+1)*DI+d]=silu(a1);
        z_silu[(size_t)(pb+2)*DI+d]=silu(a2); z_silu[(size_t)(pb+3)*DI+d]=silu(a3);
        z_silu[(size_t)(pb+4)*DI+d]=silu(a4); z_silu[(size_t)(pb+5)*DI+d]=silu(a5);
        z_silu[(size_t)(pb+6)*DI+d]=silu(a6); z_silu[(size_t)(pb+7)*DI+d]=silu(a7);
    }
}

// ---------------- Stage 2: depthwise 3x3 conv + bias + silu ------------------
__global__ __launch_bounds__(256) void k_conv(const float* __restrict__ conv_in,
    const float* __restrict__ cw, const float* __restrict__ cb,
    float* __restrict__ xc)
{
    __shared__ float scw[DI*9];
    int tid = threadIdx.x;
    for (int t = tid; t < DI*9; t += 256) scw[t] = cw[t];
    __syncthreads();
    int idx = blockIdx.x*256 + tid;
    int d = idx % DI;
    int p = (idx / DI) % LL;
    int b = idx / (DI*LL);
    int h = p / WW, w = p % WW;
    float acc = cb[d];
    #pragma unroll
    for (int dy = -1; dy <= 1; ++dy){
        int hy = h + dy; if (hy < 0 || hy >= HH) continue;
        #pragma unroll
        for (int dx = -1; dx <= 1; ++dx){
            int wx = w + dx; if (wx < 0 || wx >= WW) continue;
            acc = fmaf(conv_in[((size_t)b*LL + hy*WW + wx)*DI + d],
                       scw[d*9 + (dy+1)*3 + (dx+1)], acc);
        }
    }
    xc[idx] = silu(acc);
}

static __device__ __forceinline__ float dot4(float4 u, float4 w, float acc){
    acc = fmaf(u.x,w.x,acc); acc = fmaf(u.y,w.y,acc);
    acc = fmaf(u.z,w.z,acc); acc = fmaf(u.w,w.w,acc);
    return acc;
}

// ---------------- Stage 3: x_proj, 2 directions per block (flip symmetry) ----
// block(b,p): stages pixels in qmap(p,.) order once; weight banks k=p and k=p+2.
// Direction p+2's output row is LL-1-l (projection of flipped sequence = flipped
// projection). Weights read straight from L1/L2 (wave-broadcast addresses).
__global__ __launch_bounds__(256) void k_xproj(const float* __restrict__ xc,
   const float* __restrict__ xpw, const float* __restrict__ dtw,
   const float* __restrict__ dtb,
   float* __restrict__ delta, float* __restrict__ Bsb, float* __restrict__ Csb)
{
    __shared__ float su[XP*PAD];          // 32 x 196
    __shared__ float sxd[2][XP][40];      // 2 banks x 32 px x 38
    __shared__ float sdtw[2][DI*RK];
    int gb = blockIdx.x;
    int bp = gb / (LL/XP); int l0 = (gb % (LL/XP)) * XP;
    int b = bp >> 1, p = bp & 1;
    int kA = p, kB = p + 2;
    int bkA = b*4 + kA, bkB = b*4 + kB;
    int tid = threadIdx.x;

    for (int t = tid; t < XP*48; t += 256){
        int lo = t / 48, i4 = t % 48;
        int px = qmap(kA, l0 + lo);
        float4 u = ((const float4*)(xc + ((size_t)b*LL + px)*DI))[i4];
        *((float4*)&su[lo*PAD + i4*4]) = u;
    }
    for (int t = tid; t < DI*RK; t += 256){
        sdtw[0][t] = dtw[(size_t)kA*DI*RK + t];
        sdtw[1][t] = dtw[(size_t)kB*DI*RK + t];
    }
    __syncthreads();

    for (int q = tid; q < 19*16; q += 256){
        int c2 = q >> 4, lo = q & 15;
        int c0 = 2*c2, c1 = c0 + 1;
        const float4* pA0 = (const float4*)(xpw + ((size_t)kA*NC + c0)*DI);
        const float4* pA1 = (const float4*)(xpw + ((size_t)kA*NC + c1)*DI);
        const float4* pB0 = (const float4*)(xpw + ((size_t)kB*NC + c0)*DI);
        const float4* pB1 = (const float4*)(xpw + ((size_t)kB*NC + c1)*DI);
        const float4* ua = (const float4*)&su[lo*PAD];
        const float4* ub = (const float4*)&su[(lo+16)*PAD];
        float a00=0,a01=0,a10=0,a11=0, e00=0,e01=0,e10=0,e11=0;
        #pragma unroll 4
        for (int i4 = 0; i4 < 48; ++i4){
            float4 u0 = ua[i4], u1 = ub[i4];
            float4 wa0 = pA0[i4], wa1 = pA1[i4];
            float4 wb0 = pB0[i4], wb1 = pB1[i4];
            a00 = dot4(u0,wa0,a00); a01 = dot4(u0,wa1,a01);
            a10 = dot4(u1,wa0,a10); a11 = dot4(u1,wa1,a11);
            e00 = dot4(u0,wb0,e00); e01 = dot4(u0,wb1,e01);
            e10 = dot4(u1,wb0,e10); e11 = dot4(u1,wb1,e11);
        }
        sxd[0][lo][c0] = a00;    sxd[0][lo][c1] = a01;
        sxd[0][lo+16][c0] = a10; sxd[0][lo+16][c1] = a11;
        sxd[1][lo][c0] = e00;    sxd[1][lo][c1] = e01;
        sxd[1][lo+16][c0] = e10; sxd[1][lo+16][c1] = e11;
    }
    __syncthreads();

    for (int e = tid; e < 2*XP*DI; e += 256){
        int o = e / (XP*DI); int r2 = e % (XP*DI);
        int lo = r2 / DI, d = r2 % DI;
        int kx  = o ? kB : kA;
        int bkx = o ? bkB : bkA;
        int row = o ? (LL-1-(l0+lo)) : (l0+lo);
        float a = dtb[kx*DI + d];
        #pragma unroll
        for (int r = 0; r < RK; ++r) a = fmaf(sxd[o][lo][r], sdtw[o][d*RK + r], a);
        float sp = (a > 20.f) ? a : log1pf(__expf(a));
        delta[((size_t)bkx*LL + row)*DI + d] = sp;
    }
    for (int t = tid; t < 2*XP*NS; t += 256){
        int o = t / (XP*NS); int r2 = t % (XP*NS);
        int lo = r2 / NS, n = r2 % NS;
        int bkx = o ? bkB : bkA;
        int row = o ? (LL-1-(l0+lo)) : (l0+lo);
        Bsb[((size_t)bkx*LL + row)*NS + n] = sxd[o][lo][RK + n];
        Csb[((size_t)bkx*LL + row)*NS + n] = sxd[o][lo][RK + NS + n];
    }
}

#define HSTEP(i, comp) h[i] = fmaf(__expf(dl*An[i]), h[i], dlu*(comp))
#define YSTEP(i, comp) y = fmaf(h[i], (comp), y)

// ---------------- Stage 5 P1: local chunk recurrence, h[16] in registers -----
__global__ __launch_bounds__(192, 4) void k_scan1(const float* __restrict__ delta,
    const float* __restrict__ xc, const float* __restrict__ Bsb,
    const float* __restrict__ Alog,
    float* __restrict__ hend, float* __restrict__ sumdl)
{
    __shared__ float sB[CHL][NS];
    int bid = blockIdx.x;
    int bk = bid / NCH, ch = bid % NCH;
    int b = bk >> 2, k = bk & 3;
    int d = threadIdx.x;
    int l0 = ch*CHL;

    const float* dbase = delta + ((size_t)bk*LL + l0)*DI + d;
    const float* xbase = xc + (size_t)b*LL*DI + d;
    const float* Bb = Bsb + ((size_t)bk*LL + l0)*NS;
    for (int t = d; t < CHL*NS; t += 192) ((float*)sB)[t] = Bb[t];

    float An[NS];
    {
        const float* ab = Alog + ((size_t)k*DI + d)*NS;
        #pragma unroll
        for (int n = 0; n < NS; ++n) An[n] = -__expf(ab[n]);
    }
    __syncthreads();

    float h[NS];
    #pragma unroll
    for (int n = 0; n < NS; ++n) h[n] = 0.f;
    float S = 0.f;

    float dl_n = dbase[0];
    float uu_n = xbase[(size_t)qmap(k, l0)*DI];
    #pragma unroll 1
    for (int l = 0; l < CHL; ++l){
        float dl = dl_n, uu = uu_n;
        if (l + 1 < CHL){
            dl_n = dbase[(size_t)(l+1)*DI];
            uu_n = xbase[(size_t)qmap(k, l0+l+1)*DI];
        }
        S += dl;
        float dlu = dl * uu;
        const float4* br = (const float4*)&sB[l][0];
        float4 b0 = br[0], b1 = br[1], b2 = br[2], b3 = br[3];
        HSTEP(0,b0.x);  HSTEP(1,b0.y);  HSTEP(2,b0.z);  HSTEP(3,b0.w);
        HSTEP(4,b1.x);  HSTEP(5,b1.y);  HSTEP(6,b1.z);  HSTEP(7,b1.w);
        HSTEP(8,b2.x);  HSTEP(9,b2.y);  HSTEP(10,b2.z); HSTEP(11,b2.w);
        HSTEP(12,b3.x); HSTEP(13,b3.y); HSTEP(14,b3.z); HSTEP(15,b3.w);
    }
    size_t hb = ((size_t)bk*NCH + ch)*NS*DI + d;
    #pragma unroll
    for (int n = 0; n < NS; ++n) hend[hb + (size_t)n*DI] = h[n];
    sumdl[((size_t)bk*NCH + ch)*DI + d] = S;
}

// ---------------- Stage 5 P2: combine chunk states in-place (hend -> H0) -----
__global__ __launch_bounds__(256) void k_scan2(float* __restrict__ hend,
    const float* __restrict__ sumdl, const float* __restrict__ Alog)
{
    int blk = blockIdx.x;
    int bk = blk / NDT, part = blk % NDT;
    int k = bk & 3;
    int tid = threadIdx.x;
    int dsub = tid & 15, n = tid >> 4;
    int d = part*16 + dsub;
    float An = -__expf(Alog[((size_t)k*DI + d)*NS + n]);
    size_t base  = ((size_t)bk*NCH)*NS*DI + (size_t)n*DI + d;
    size_t sbase = (size_t)bk*NCH*DI + d;
    float H = 0.f;
    float he = hend[base], S = sumdl[sbase];
    for (int c = 0; c < NCH; ++c){
        float heN = 0.f, SN = 0.f;
        if (c+1 < NCH){
            heN = hend [base  + (size_t)(c+1)*NS*DI];
            SN  = sumdl[sbase + (size_t)(c+1)*DI];
        }
        hend[base + (size_t)c*NS*DI] = H;
        H  = fmaf(__expf(An*S), H, he);
        he = heN; S = SN;
    }
}

// ---------------- Stage 5 P3: full recurrence from H0, emit y ---------------
__global__ __launch_bounds__(192, 4) void k_scan3(const float* __restrict__ delta,
    const float* __restrict__ xc, const float* __restrict__ Bsb,
    const float* __restrict__ Csb, const float* __restrict__ Alog,
    const float* __restrict__ Dsv, const float* __restrict__ H0,
    float* __restrict__ y_acc)
{
    __shared__ float sB[CHL][NS], sC[CHL][NS];
    int bid = blockIdx.x;
    int bk = bid / NCH, ch = bid % NCH;
    int b = bk >> 2, k = bk & 3;
    int d = threadIdx.x;
    int l0 = ch*CHL;

    const float* dbase = delta + ((size_t)bk*LL + l0)*DI + d;
    const float* xbase = xc + (size_t)b*LL*DI + d;
    const float* Bb = Bsb + ((size_t)bk*LL + l0)*NS;
    const float* Cb = Csb + ((size_t)bk*LL + l0)*NS;
    float* ybase = y_acc + (size_t)b*LL*DI + d;
    for (int t = d; t < CHL*NS; t += 192){
        ((float*)sB)[t] = Bb[t];
        ((float*)sC)[t] = Cb[t];
    }

    float An[NS];
    {
        const float* ab = Alog + ((size_t)k*DI + d)*NS;
        #pragma unroll
        for (int n = 0; n < NS; ++n) An[n] = -__expf(ab[n]);
    }
    float Dv = Dsv[k*DI + d];

    float h[NS];
    size_t hb = ((size_t)bk*NCH + ch)*NS*DI + d;
    #pragma unroll
    for (int n = 0; n < NS; ++n) h[n] = H0[hb + (size_t)n*DI];
    __syncthreads();

    int   q_n  = qmap(k, l0);
    float dl_n = dbase[0];
    float uu_n = xbase[(size_t)q_n*DI];
    #pragma unroll 1
    for (int l = 0; l < CHL; ++l){
        float dl = dl_n, uu = uu_n;
        int q = q_n;
        if (l + 1 < CHL){
            q_n  = qmap(k, l0+l+1);
            dl_n = dbase[(size_t)(l+1)*DI];
            uu_n = xbase[(size_t)q_n*DI];
        }
        float dlu = dl * uu;
        const float4* br = (const float4*)&sB[l][0];
        const float4* cr = (const float4*)&sC[l][0];
        float4 b0 = br[0], b1 = br[1], b2 = br[2], b3 = br[3];
        HSTEP(0,b0.x);  HSTEP(1,b0.y);  HSTEP(2,b0.z);  HSTEP(3,b0.w);
        HSTEP(4,b1.x);  HSTEP(5,b1.y);  HSTEP(6,b1.z);  HSTEP(7,b1.w);
        HSTEP(8,b2.x);  HSTEP(9,b2.y);  HSTEP(10,b2.z); HSTEP(11,b2.w);
        HSTEP(12,b3.x); HSTEP(13,b3.y); HSTEP(14,b3.z); HSTEP(15,b3.w);
        float4 c0 = cr[0], c1 = cr[1], c2 = cr[2], c3 = cr[3];
        float y = uu * Dv;
        YSTEP(0,c0.x);  YSTEP(1,c0.y);  YSTEP(2,c0.z);  YSTEP(3,c0.w);
        YSTEP(4,c1.x);  YSTEP(5,c1.y);  YSTEP(6,c1.z);  YSTEP(7,c1.w);
        YSTEP(8,c2.x);  YSTEP(9,c2.y);  YSTEP(10,c2.z); YSTEP(11,c2.w);
        YSTEP(12,c3.x); YSTEP(13,c3.y); YSTEP(14,c3.z); YSTEP(15,c3.w);
        atomicAdd(&ybase[(size_t)q*DI], y);
    }
}

// ---------------- Stage 6: LN + z-gate + out_proj, 8 px/block ----------------
__global__ __launch_bounds__(192) void k_lnout(const float* __restrict__ y_acc,
    const float* __restrict__ z_silu, const float* __restrict__ lnw,
    const float* __restrict__ lnb, const float* __restrict__ WoutT,
    float* __restrict__ out)
{
    __shared__ float syz[LNPX][DI];
    __shared__ float red_s[LNPX][3], red_q[LNPX][3];
    __shared__ float smu[LNPX], srs[LNPX];
    int pg0 = blockIdx.x * LNPX;
    int tid = threadIdx.x;
    float wln = lnw[tid], bln = lnb[tid];
    float v[LNPX];
    #pragma unroll
    for (int px = 0; px < LNPX; ++px)
        v[px] = y_acc[(size_t)(pg0+px)*DI + tid];
    int wid = tid >> 6, lane = tid & 63;
    #pragma unroll
    for (int px = 0; px < LNPX; ++px){
        float s = v[px], sq = v[px]*v[px];
        #pragma unroll
        for (int m = 32; m >= 1; m >>= 1){ s += __shfl_xor(s,m); sq += __shfl_xor(sq,m); }
        if (lane == 0){ red_s[px][wid] = s; red_q[px][wid] = sq; }
    }
    __syncthreads();
    if (tid < LNPX){
        float ts = red_s[tid][0]+red_s[tid][1]+red_s[tid][2];
        float tq = red_q[tid][0]+red_q[tid][1]+red_q[tid][2];
        float mu = ts*(1.f/DI);
        float var = tq*(1.f/DI) - mu*mu;
        smu[tid] = mu; srs[tid] = rsqrtf(var + 1e-5f);
    }
    __syncthreads();
    #pragma unroll
    for (int px = 0; px < LNPX; ++px){
        float z = z_silu[(size_t)(pg0+px)*DI + tid];
        syz[px][tid] = ((v[px]-smu[px])*srs[px]*wln + bln) * z;
    }
    __syncthreads();
    // matvec: group g = tid/96 handles pixels g*4..g*4+3, output col c = tid%96
    int g = tid / DM, c = tid % DM;
    float a0=0,a1=0,a2=0,a3=0;
    for (int i = 0; i < DI; ++i){
        float w = WoutT[(size_t)i*DM + c];
        a0 = fmaf(syz[g*4+0][i], w, a0);
        a1 = fmaf(syz[g*4+1][i], w, a1);
        a2 = fmaf(syz[g*4+2][i], w, a2);
        a3 = fmaf(syz[g*4+3][i], w, a3);
    }
    out[(size_t)(pg0+g*4+0)*DM + c] = a0;
    out[(size_t)(pg0+g*4+1)*DM + c] = a1;
    out[(size_t)(pg0+g*4+2)*DM + c] = a2;
    out[(size_t)(pg0+g*4+3)*DM + c] = a3;
}

extern "C" void kernel_launch(void* const* d_in, const int* in_sizes, int n_in,
                              void* d_out, int out_size, void* d_ws, size_t ws_size,
                              hipStream_t stream)
{
    const float* x    = (const float*)d_in[0];
    const float* Win  = (const float*)d_in[1];
    const float* cw   = (const float*)d_in[2];
    const float* cb   = (const float*)d_in[3];
    const float* xpw  = (const float*)d_in[4];
    const float* dtw  = (const float*)d_in[5];
    const float* dtb  = (const float*)d_in[6];
    const float* Alog = (const float*)d_in[7];
    const float* Dsv  = (const float*)d_in[8];
    const float* lnw  = (const float*)d_in[9];
    const float* lnb  = (const float*)d_in[10];
    const float* Wout = (const float*)d_in[11];
    float* out = (float*)d_out;

    float* ws      = (float*)d_ws;
    float* conv_in = ws;                                    // [NPIX,DI] dead after k_conv
    float* z_silu  = conv_in + (size_t)NPIX*DI;             // [NPIX,DI]
    float* xc      = z_silu  + (size_t)NPIX*DI;             // [NPIX,DI] live through P3
    float* delta   = xc      + (size_t)NPIX*DI;             // [16,LL,DI]
    float* Bsb     = delta   + (size_t)BB*KG*LL*DI;         // [16,LL,NS]
    float* Csb     = Bsb     + (size_t)BB*KG*LL*NS;         // [16,LL,NS]
    float* sumdl   = Csb     + (size_t)BB*KG*LL*NS;         // [16,49,DI]
    float* y_acc   = sumdl   + (size_t)BB*KG*NCH*DI;        // [NPIX,DI]
    float* WinT    = y_acc   + (size_t)NPIX*DI;             // [96,384]
    float* WoutT   = WinT    + (size_t)DM*2*DI;             // [192,96]
    float* hend    = conv_in;  // alias: [16,49,NS,DI] == NPIX*DI; H0 in-place after P2

    hipLaunchKernelGGL(k_prep,   dim3((384*DM + DI*DM + 255)/256), dim3(256), 0, stream,
                       Win, Wout, WinT, WoutT);
    hipLaunchKernelGGL(k_inproj, dim3(NPIX/8), dim3(384), 0, stream, x, WinT, conv_in, z_silu);
    hipLaunchKernelGGL(k_conv,   dim3((NPIX*DI)/256), dim3(256), 0, stream, conv_in, cw, cb, xc);
    hipLaunchKernelGGL(k_xproj,  dim3(BB*2*(LL/XP)), dim3(256), 0, stream, xc, xpw, dtw, dtb, delta, Bsb, Csb);
    hipMemsetAsync(y_acc, 0, (size_t)NPIX*DI*sizeof(float), stream);
    hipLaunchKernelGGL(k_scan1, dim3(BB*KG*NCH), dim3(192), 0, stream,
                       delta, xc, Bsb, Alog, hend, sumdl);
    hipLaunchKernelGGL(k_scan2, dim3(BB*KG*NDT), dim3(256), 0, stream,
                       hend, sumdl, Alog);
    hipLaunchKernelGGL(k_scan3, dim3(BB*KG*NCH), dim3(192), 0, stream,
                       delta, xc, Bsb, Csb, Alog, Dsv, hend, y_acc);
    hipLaunchKernelGGL(k_lnout,  dim3(NPIX/LNPX), dim3(192), 0, stream, y_acc, z_silu, lnw, lnb, WoutT, out);
}

// Round 8
// 338.646 us; speedup vs baseline: 2.2933x; 1.0865x over previous
//
#include <hip/hip_runtime.h>
#include <hip/hip_bf16.h>
#include <math.h>

#define BB 4
#define HH 56
#define WW 56
#define DM 96
#define DI 192
#define NS 16
#define RK 6
#define KG 4
#define LL (HH*WW)          // 3136
#define NPIX (BB*LL)        // 12544
#define CHL 64              // scan chunk length
#define NCH (LL/CHL)        // 49 chunks
#define NDT (DI/16)         // 12
#define XP 32               // xproj pixels per block
#define NC 38               // RK + 2*NS
#define PAD 196             // padded row length
#define LNPX 8              // lnout pixels per block

static __device__ __forceinline__ int qmap(int k, int l){
    int m = (k & 2) ? (LL - 1 - l) : l;
    if (k & 1) { int w = m / HH; int h = m % HH; return h * WW + w; }
    return m;
}

static __device__ __forceinline__ float silu(float x){ return x / (1.f + __expf(-x)); }

// ---------------- Stage 0: transpose weights (one-time, tiny) ----------------
__global__ __launch_bounds__(256) void k_prep(const float* __restrict__ Win,
    const float* __restrict__ Wout, const float* __restrict__ dtw,
    float* __restrict__ WinT, float* __restrict__ WoutT, float* __restrict__ dtwT)
{
    int t = blockIdx.x*256 + threadIdx.x;
    if (t < 384*DM){                 // WinT[i*384+c] = Win[c*96+i]
        int i = t / 384, c = t % 384;
        WinT[t] = Win[(size_t)c*DM + i];
    } else if (t < 384*DM + DI*DM){  // WoutT[i*96+c] = Wout[c*192+i]
        int t2 = t - 384*DM;
        int i = t2 / DM, c = t2 % DM;
        WoutT[t2] = Wout[(size_t)c*DI + i];
    } else if (t < 384*DM + DI*DM + KG*RK*DI){  // dtwT[k][r][d] = dtw[k][d][r]
        int t2 = t - 384*DM - DI*DM;
        int k = t2 / (RK*DI);
        int r = (t2 % (RK*DI)) / DI;
        int d = t2 % DI;
        dtwT[t2] = dtw[((size_t)k*DI + d)*RK + r];
    }
}

// ---------------- Stage 1: in_proj, 8 px/block, coalesced WinT ---------------
__global__ __launch_bounds__(384) void k_inproj(const float* __restrict__ x,
        const float* __restrict__ WinT,
        float* __restrict__ conv_in, float* __restrict__ z_silu)
{
    __shared__ float sx[8*DM];
    int pb  = blockIdx.x * 8;
    int c = threadIdx.x;
    sx[c]       = x[(size_t)pb*DM + c];
    sx[c + 384] = x[(size_t)pb*DM + 384 + c];
    __syncthreads();
    float a0=0,a1=0,a2=0,a3=0,a4=0,a5=0,a6=0,a7=0;
    for (int i = 0; i < DM; ++i){
        float w = WinT[(size_t)i*384 + c];          // lane-coalesced
        a0=fmaf(sx[i],w,a0);        a1=fmaf(sx[DM+i],w,a1);
        a2=fmaf(sx[2*DM+i],w,a2);   a3=fmaf(sx[3*DM+i],w,a3);
        a4=fmaf(sx[4*DM+i],w,a4);   a5=fmaf(sx[5*DM+i],w,a5);
        a6=fmaf(sx[6*DM+i],w,a6);   a7=fmaf(sx[7*DM+i],w,a7);
    }
    if (c < DI){
        conv_in[(size_t)(pb+0)*DI+c]=a0; conv_in[(size_t)(pb+1)*DI+c]=a1;
        conv_in[(size_t)(pb+2)*DI+c]=a2; conv_in[(size_t)(pb+3)*DI+c]=a3;
        conv_in[(size_t)(pb+4)*DI+c]=a4; conv_in[(size_t)(pb+5)*DI+c]=a5;
        conv_in[(size_t)(pb+6)*DI+c]=a6; conv_in[(size_t)(pb+7)*DI+c]=a7;
    } else {
        int d = c - DI;
        z_silu[(size_t)(pb+0)*DI+d]=silu(a0); z_silu[(size_t)(pb+1)*DI+d]=silu(a1);
        z_silu[(size_t)(pb+2)*DI+d]=silu(a2); z_silu[(size_t)(pb+3)*DI+d]=silu(a3);
        z_silu[(size_t)(pb+4)*DI+d]=silu(a4); z_silu[(size_t)(pb+5)*DI+d]=silu(a5);
        z_silu[(size_t)(pb+6)*DI+d]=silu(a6); z_silu[(size_t)(pb+7)*DI+d]=silu(a7);
    }
}

// ---------------- Stage 2: depthwise 3x3 conv + bias + silu ------------------
__global__ __launch_bounds__(256) void k_conv(const float* __restrict__ conv_in,
    const float* __restrict__ cw, const float* __restrict__ cb,
    float* __restrict__ xc)
{
    __shared__ float scw[DI*9];
    int tid = threadIdx.x;
    for (int t = tid; t < DI*9; t += 256) scw[t] = cw[t];
    __syncthreads();
    int idx = blockIdx.x*256 + tid;
    int d = idx % DI;
    int p = (idx / DI) % LL;
    int b = idx / (DI*LL);
    int h = p / WW, w = p % WW;
    float acc = cb[d];
    #pragma unroll
    for (int dy = -1; dy <= 1; ++dy){
        int hy = h + dy; if (hy < 0 || hy >= HH) continue;
        #pragma unroll
        for (int dx = -1; dx <= 1; ++dx){
            int wx = w + dx; if (wx < 0 || wx >= WW) continue;
            acc = fmaf(conv_in[((size_t)b*LL + hy*WW + wx)*DI + d],
                       scw[d*9 + (dy+1)*3 + (dx+1)], acc);
        }
    }
    xc[idx] = silu(acc);
}

static __device__ __forceinline__ float dot4(float4 u, float4 w, float acc){
    acc = fmaf(u.x,w.x,acc); acc = fmaf(u.y,w.y,acc);
    acc = fmaf(u.z,w.z,acc); acc = fmaf(u.w,w.w,acc);
    return acc;
}

// ---------------- Stage 3: x_proj, 2 directions/block, block=320 -------------
// 304 GEMM tasks in a single pass; weights straight from L1/L2; also zeroes
// its slice of y_acc (replaces the memset dispatch).
__global__ __launch_bounds__(320, 5) void k_xproj(const float* __restrict__ xc,
   const float* __restrict__ xpw, const float* __restrict__ dtwT,
   const float* __restrict__ dtb,
   float* __restrict__ delta, float* __restrict__ Bsb, float* __restrict__ Csb,
   float* __restrict__ y_acc)
{
    __shared__ float su[XP*PAD];          // 32 x 196  (25.1 KB)
    __shared__ float sxd[2][XP][40];      // 10.2 KB
    int gb = blockIdx.x;
    int bp = gb / (LL/XP); int l0 = (gb % (LL/XP)) * XP;
    int b = bp >> 1, p = bp & 1;
    int kA = p, kB = p + 2;
    int bkA = b*4 + kA, bkB = b*4 + kB;
    int tid = threadIdx.x;

    // zero this block's slice of y_acc (768 float4 per block, exact)
    {
        float4* yz = (float4*)y_acc + (size_t)gb*768;
        float4 z4 = make_float4(0.f,0.f,0.f,0.f);
        for (int t = tid; t < 768; t += 320) yz[t] = z4;
    }

    for (int t = tid; t < XP*48; t += 320){
        int lo = t / 48, i4 = t % 48;
        int px = qmap(kA, l0 + lo);
        float4 u = ((const float4*)(xc + ((size_t)b*LL + px)*DI))[i4];
        *((float4*)&su[lo*PAD + i4*4]) = u;
    }
    __syncthreads();

    for (int q = tid; q < 19*16; q += 320){
        int c2 = q >> 4, lo = q & 15;
        int c0 = 2*c2, c1 = c0 + 1;
        const float4* pA0 = (const float4*)(xpw + ((size_t)kA*NC + c0)*DI);
        const float4* pA1 = (const float4*)(xpw + ((size_t)kA*NC + c1)*DI);
        const float4* pB0 = (const float4*)(xpw + ((size_t)kB*NC + c0)*DI);
        const float4* pB1 = (const float4*)(xpw + ((size_t)kB*NC + c1)*DI);
        const float4* ua = (const float4*)&su[lo*PAD];
        const float4* ub = (const float4*)&su[(lo+16)*PAD];
        float a00=0,a01=0,a10=0,a11=0, e00=0,e01=0,e10=0,e11=0;
        #pragma unroll 4
        for (int i4 = 0; i4 < 48; ++i4){
            float4 u0 = ua[i4], u1 = ub[i4];
            float4 wa0 = pA0[i4], wa1 = pA1[i4];
            float4 wb0 = pB0[i4], wb1 = pB1[i4];
            a00 = dot4(u0,wa0,a00); a01 = dot4(u0,wa1,a01);
            a10 = dot4(u1,wa0,a10); a11 = dot4(u1,wa1,a11);
            e00 = dot4(u0,wb0,e00); e01 = dot4(u0,wb1,e01);
            e10 = dot4(u1,wb0,e10); e11 = dot4(u1,wb1,e11);
        }
        sxd[0][lo][c0] = a00;    sxd[0][lo][c1] = a01;
        sxd[0][lo+16][c0] = a10; sxd[0][lo+16][c1] = a11;
        sxd[1][lo][c0] = e00;    sxd[1][lo][c1] = e01;
        sxd[1][lo+16][c0] = e10; sxd[1][lo+16][c1] = e11;
    }
    __syncthreads();

    for (int e = tid; e < 2*XP*DI; e += 320){
        int o = e / (XP*DI); int r2 = e % (XP*DI);
        int lo = r2 / DI, d = r2 % DI;
        int kx  = o ? kB : kA;
        int bkx = o ? bkB : bkA;
        int row = o ? (LL-1-(l0+lo)) : (l0+lo);
        float a = dtb[kx*DI + d];
        const float* wt = dtwT + (size_t)kx*RK*DI + d;
        #pragma unroll
        for (int r = 0; r < RK; ++r) a = fmaf(sxd[o][lo][r], wt[(size_t)r*DI], a);
        float sp = (a > 20.f) ? a : __logf(1.f + __expf(a));
        delta[((size_t)bkx*LL + row)*DI + d] = sp;
    }
    for (int t = tid; t < 2*XP*NS; t += 320){
        int o = t / (XP*NS); int r2 = t % (XP*NS);
        int lo = r2 / NS, n = r2 % NS;
        int bkx = o ? bkB : bkA;
        int row = o ? (LL-1-(l0+lo)) : (l0+lo);
        Bsb[((size_t)bkx*LL + row)*NS + n] = sxd[o][lo][RK + n];
        Csb[((size_t)bkx*LL + row)*NS + n] = sxd[o][lo][RK + NS + n];
    }
}

#define HSTEP(i, comp) h[i] = fmaf(__expf(dl*An[i]), h[i], dlu*(comp))
#define YSTEP(i, comp) y = fmaf(h[i], (comp), y)

// ---------------- Stage 5 P1: local chunk recurrence, split over n-halves ----
// grid: bk(16) x ch(49) x nh(2) = 1568; block 192 (one per d); h[8]/thread.
__global__ __launch_bounds__(192, 5) void k_scan1(const float* __restrict__ delta,
    const float* __restrict__ xc, const float* __restrict__ Bsb,
    const float* __restrict__ Alog,
    float* __restrict__ hend, float* __restrict__ sumdl)
{
    __shared__ float sB[CHL][8];
    int bid = blockIdx.x;
    int nh = bid & 1;
    int ch = (bid >> 1) % NCH;
    int bk = bid / (2*NCH);
    int b = bk >> 2, k = bk & 3;
    int d = threadIdx.x;
    int l0 = ch*CHL;

    const float* dbase = delta + ((size_t)bk*LL + l0)*DI + d;
    const float* xbase = xc + (size_t)b*LL*DI + d;
    const float* Bb = Bsb + ((size_t)bk*LL + l0)*NS + nh*8;
    for (int t = d; t < CHL*8; t += 192){
        int l = t >> 3, j = t & 7;
        sB[l][j] = Bb[(size_t)l*NS + j];
    }

    float An[8];
    {
        const float* ab = Alog + ((size_t)k*DI + d)*NS + nh*8;
        #pragma unroll
        for (int j = 0; j < 8; ++j) An[j] = -__expf(ab[j]);
    }
    __syncthreads();

    float h[8];
    #pragma unroll
    for (int j = 0; j < 8; ++j) h[j] = 0.f;
    float S = 0.f;

    float dl_n = dbase[0];
    float uu_n = xbase[(size_t)qmap(k, l0)*DI];
    #pragma unroll 1
    for (int l = 0; l < CHL; ++l){
        float dl = dl_n, uu = uu_n;
        if (l + 1 < CHL){
            dl_n = dbase[(size_t)(l+1)*DI];
            uu_n = xbase[(size_t)qmap(k, l0+l+1)*DI];
        }
        S += dl;
        float dlu = dl * uu;
        const float4* br = (const float4*)&sB[l][0];
        float4 b0 = br[0], b1 = br[1];
        HSTEP(0,b0.x); HSTEP(1,b0.y); HSTEP(2,b0.z); HSTEP(3,b0.w);
        HSTEP(4,b1.x); HSTEP(5,b1.y); HSTEP(6,b1.z); HSTEP(7,b1.w);
    }
    size_t hb = ((size_t)bk*NCH + ch)*NS*DI + (size_t)nh*8*DI + d;
    #pragma unroll
    for (int j = 0; j < 8; ++j) hend[hb + (size_t)j*DI] = h[j];
    if (nh == 0) sumdl[((size_t)bk*NCH + ch)*DI + d] = S;
}

// ---------------- Stage 5 P2: combine chunk states in-place (hend -> H0) -----
__global__ __launch_bounds__(256) void k_scan2(float* __restrict__ hend,
    const float* __restrict__ sumdl, const float* __restrict__ Alog)
{
    int blk = blockIdx.x;
    int bk = blk / NDT, part = blk % NDT;
    int k = bk & 3;
    int tid = threadIdx.x;
    int dsub = tid & 15, n = tid >> 4;
    int d = part*16 + dsub;
    float An = -__expf(Alog[((size_t)k*DI + d)*NS + n]);
    size_t base  = ((size_t)bk*NCH)*NS*DI + (size_t)n*DI + d;
    size_t sbase = (size_t)bk*NCH*DI + d;
    float H = 0.f;
    float he = hend[base], S = sumdl[sbase];
    for (int c = 0; c < NCH; ++c){
        float heN = 0.f, SN = 0.f;
        if (c+1 < NCH){
            heN = hend [base  + (size_t)(c+1)*NS*DI];
            SN  = sumdl[sbase + (size_t)(c+1)*DI];
        }
        hend[base + (size_t)c*NS*DI] = H;
        H  = fmaf(__expf(An*S), H, he);
        he = heN; S = SN;
    }
}

// ---------------- Stage 5 P3: full recurrence from H0, split over n-halves ---
__global__ __launch_bounds__(192, 5) void k_scan3(const float* __restrict__ delta,
    const float* __restrict__ xc, const float* __restrict__ Bsb,
    const float* __restrict__ Csb, const float* __restrict__ Alog,
    const float* __restrict__ Dsv, const float* __restrict__ H0,
    float* __restrict__ y_acc)
{
    __shared__ float sB[CHL][8], sC[CHL][8];
    int bid = blockIdx.x;
    int nh = bid & 1;
    int ch = (bid >> 1) % NCH;
    int bk = bid / (2*NCH);
    int b = bk >> 2, k = bk & 3;
    int d = threadIdx.x;
    int l0 = ch*CHL;

    const float* dbase = delta + ((size_t)bk*LL + l0)*DI + d;
    const float* xbase = xc + (size_t)b*LL*DI + d;
    const float* Bb = Bsb + ((size_t)bk*LL + l0)*NS + nh*8;
    const float* Cb = Csb + ((size_t)bk*LL + l0)*NS + nh*8;
    float* ybase = y_acc + (size_t)b*LL*DI + d;
    for (int t = d; t < CHL*8; t += 192){
        int l = t >> 3, j = t & 7;
        sB[l][j] = Bb[(size_t)l*NS + j];
        sC[l][j] = Cb[(size_t)l*NS + j];
    }

    float An[8];
    {
        const float* ab = Alog + ((size_t)k*DI + d)*NS + nh*8;
        #pragma unroll
        for (int j = 0; j < 8; ++j) An[j] = -__expf(ab[j]);
    }
    float Dv = (nh == 0) ? Dsv[k*DI + d] : 0.f;

    float h[8];
    size_t hb = ((size_t)bk*NCH + ch)*NS*DI + (size_t)nh*8*DI + d;
    #pragma unroll
    for (int j = 0; j < 8; ++j) h[j] = H0[hb + (size_t)j*DI];
    __syncthreads();

    int   q_n  = qmap(k, l0);
    float dl_n = dbase[0];
    float uu_n = xbase[(size_t)q_n*DI];
    #pragma unroll 1
    for (int l = 0; l < CHL; ++l){
        float dl = dl_n, uu = uu_n;
        int q = q_n;
        if (l + 1 < CHL){
            q_n  = qmap(k, l0+l+1);
            dl_n = dbase[(size_t)(l+1)*DI];
            uu_n = xbase[(size_t)q_n*DI];
        }
        float dlu = dl * uu;
        const float4* br = (const float4*)&sB[l][0];
        const float4* cr = (const float4*)&sC[l][0];
        float4 b0 = br[0], b1 = br[1];
        HSTEP(0,b0.x); HSTEP(1,b0.y); HSTEP(2,b0.z); HSTEP(3,b0.w);
        HSTEP(4,b1.x); HSTEP(5,b1.y); HSTEP(6,b1.z); HSTEP(7,b1.w);
        float4 c0 = cr[0], c1 = cr[1];
        float y = uu * Dv;
        YSTEP(0,c0.x); YSTEP(1,c0.y); YSTEP(2,c0.z); YSTEP(3,c0.w);
        YSTEP(4,c1.x); YSTEP(5,c1.y); YSTEP(6,c1.z); YSTEP(7,c1.w);
        atomicAdd(&ybase[(size_t)q*DI], y);
    }
}

// ---------------- Stage 6: LN + z-gate + out_proj, 8 px/block ----------------
__global__ __launch_bounds__(192) void k_lnout(const float* __restrict__ y_acc,
    const float* __restrict__ z_silu, const float* __restrict__ lnw,
    const float* __restrict__ lnb, const float* __restrict__ WoutT,
    float* __restrict__ out)
{
    __shared__ float syz[LNPX][DI];
    __shared__ float red_s[LNPX][3], red_q[LNPX][3];
    __shared__ float smu[LNPX], srs[LNPX];
    int pg0 = blockIdx.x * LNPX;
    int tid = threadIdx.x;
    float wln = lnw[tid], bln = lnb[tid];
    float v[LNPX];
    #pragma unroll
    for (int px = 0; px < LNPX; ++px)
        v[px] = y_acc[(size_t)(pg0+px)*DI + tid];
    int wid = tid >> 6, lane = tid & 63;
    #pragma unroll
    for (int px = 0; px < LNPX; ++px){
        float s = v[px], sq = v[px]*v[px];
        #pragma unroll
        for (int m = 32; m >= 1; m >>= 1){ s += __shfl_xor(s,m); sq += __shfl_xor(sq,m); }
        if (lane == 0){ red_s[px][wid] = s; red_q[px][wid] = sq; }
    }
    __syncthreads();
    if (tid < LNPX){
        float ts = red_s[tid][0]+red_s[tid][1]+red_s[tid][2];
        float tq = red_q[tid][0]+red_q[tid][1]+red_q[tid][2];
        float mu = ts*(1.f/DI);
        float var = tq*(1.f/DI) - mu*mu;
        smu[tid] = mu; srs[tid] = rsqrtf(var + 1e-5f);
    }
    __syncthreads();
    #pragma unroll
    for (int px = 0; px < LNPX; ++px){
        float z = z_silu[(size_t)(pg0+px)*DI + tid];
        syz[px][tid] = ((v[px]-smu[px])*srs[px]*wln + bln) * z;
    }
    __syncthreads();
    int g = tid / DM, c = tid % DM;
    float a0=0,a1=0,a2=0,a3=0;
    for (int i = 0; i < DI; ++i){
        float w = WoutT[(size_t)i*DM + c];
        a0 = fmaf(syz[g*4+0][i], w, a0);
        a1 = fmaf(syz[g*4+1][i], w, a1);
        a2 = fmaf(syz[g*4+2][i], w, a2);
        a3 = fmaf(syz[g*4+3][i], w, a3);
    }
    out[(size_t)(pg0+g*4+0)*DM + c] = a0;
    out[(size_t)(pg0+g*4+1)*DM + c] = a1;
    out[(size_t)(pg0+g*4+2)*DM + c] = a2;
    out[(size_t)(pg0+g*4+3)*DM + c] = a3;
}

extern "C" void kernel_launch(void* const* d_in, const int* in_sizes, int n_in,
                              void* d_out, int out_size, void* d_ws, size_t ws_size,
                              hipStream_t stream)
{
    const float* x    = (const float*)d_in[0];
    const float* Win  = (const float*)d_in[1];
    const float* cw   = (const float*)d_in[2];
    const float* cb   = (const float*)d_in[3];
    const float* xpw  = (const float*)d_in[4];
    const float* dtw  = (const float*)d_in[5];
    const float* dtb  = (const float*)d_in[6];
    const float* Alog = (const float*)d_in[7];
    const float* Dsv  = (const float*)d_in[8];
    const float* lnw  = (const float*)d_in[9];
    const float* lnb  = (const float*)d_in[10];
    const float* Wout = (const float*)d_in[11];
    float* out = (float*)d_out;

    float* ws      = (float*)d_ws;
    float* conv_in = ws;                                    // [NPIX,DI] dead after k_conv
    float* z_silu  = conv_in + (size_t)NPIX*DI;             // [NPIX,DI]
    float* xc      = z_silu  + (size_t)NPIX*DI;             // [NPIX,DI] live through P3
    float* delta   = xc      + (size_t)NPIX*DI;             // [16,LL,DI]
    float* Bsb     = delta   + (size_t)BB*KG*LL*DI;         // [16,LL,NS]
    float* Csb     = Bsb     + (size_t)BB*KG*LL*NS;         // [16,LL,NS]
    float* sumdl   = Csb     + (size_t)BB*KG*LL*NS;         // [16,49,DI]
    float* y_acc   = sumdl   + (size_t)BB*KG*NCH*DI;        // [NPIX,DI]
    float* WinT    = y_acc   + (size_t)NPIX*DI;             // [96,384]
    float* WoutT   = WinT    + (size_t)DM*2*DI;             // [192,96]
    float* dtwT    = WoutT   + (size_t)DI*DM;               // [4,6,192]
    float* hend    = conv_in;  // alias: [16,49,16,192] == NPIX*DI; H0 in-place after P2

    hipLaunchKernelGGL(k_prep,   dim3((384*DM + DI*DM + KG*RK*DI + 255)/256), dim3(256), 0, stream,
                       Win, Wout, dtw, WinT, WoutT, dtwT);
    hipLaunchKernelGGL(k_inproj, dim3(NPIX/8), dim3(384), 0, stream, x, WinT, conv_in, z_silu);
    hipLaunchKernelGGL(k_conv,   dim3((NPIX*DI)/256), dim3(256), 0, stream, conv_in, cw, cb, xc);
    hipLaunchKernelGGL(k_xproj,  dim3(BB*2*(LL/XP)), dim3(320), 0, stream, xc, xpw, dtwT, dtb,
                       delta, Bsb, Csb, y_acc);
    hipLaunchKernelGGL(k_scan1, dim3(BB*KG*NCH*2), dim3(192), 0, stream,
                       delta, xc, Bsb, Alog, hend, sumdl);
    hipLaunchKernelGGL(k_scan2, dim3(BB*KG*NDT), dim3(256), 0, stream,
                       hend, sumdl, Alog);
    hipLaunchKernelGGL(k_scan3, dim3(BB*KG*NCH*2), dim3(192), 0, stream,
                       delta, xc, Bsb, Csb, Alog, Dsv, hend, y_acc);
    hipLaunchKernelGGL(k_lnout,  dim3(NPIX/LNPX), dim3(192), 0, stream, y_acc, z_silu, lnw, lnb, WoutT, out);
}

// Round 9
// 323.272 us; speedup vs baseline: 2.4024x; 1.0476x over previous
//
#include <hip/hip_runtime.h>
#include <hip/hip_bf16.h>
#include <math.h>

#define BB 4
#define HH 56
#define WW 56
#define DM 96
#define DI 192
#define NS 16
#define RK 6
#define KG 4
#define LL (HH*WW)          // 3136
#define NPIX (BB*LL)        // 12544
#define CHL 64              // scan chunk length
#define NCH (LL/CHL)        // 49 chunks
#define NDT (DI/16)         // 12
#define XP 32               // xproj pixels per block
#define NC 38               // RK + 2*NS
#define PAD 196             // padded row length
#define LNPX 8              // lnout pixels per block

static __device__ __forceinline__ int qmap(int k, int l){
    int m = (k & 2) ? (LL - 1 - l) : l;
    if (k & 1) { int w = m / HH; int h = m % HH; return h * WW + w; }
    return m;
}

static __device__ __forceinline__ float silu(float x){ return x / (1.f + __expf(-x)); }

// ---------------- Stage 0: transpose weights (one-time, tiny) ----------------
__global__ __launch_bounds__(256) void k_prep(const float* __restrict__ Win,
    const float* __restrict__ Wout, const float* __restrict__ dtw,
    float* __restrict__ WinT, float* __restrict__ WoutT, float* __restrict__ dtwT)
{
    int t = blockIdx.x*256 + threadIdx.x;
    if (t < 384*DM){                 // WinT[i*384+c] = Win[c*96+i]
        int i = t / 384, c = t % 384;
        WinT[t] = Win[(size_t)c*DM + i];
    } else if (t < 384*DM + DI*DM){  // WoutT[i*96+c] = Wout[c*192+i]
        int t2 = t - 384*DM;
        int i = t2 / DM, c = t2 % DM;
        WoutT[t2] = Wout[(size_t)c*DI + i];
    } else if (t < 384*DM + DI*DM + KG*RK*DI){  // dtwT[k][r][d] = dtw[k][d][r]
        int t2 = t - 384*DM - DI*DM;
        int k = t2 / (RK*DI);
        int r = (t2 % (RK*DI)) / DI;
        int d = t2 % DI;
        dtwT[t2] = dtw[((size_t)k*DI + d)*RK + r];
    }
}

// ---------------- Stage 1: in_proj, 8 px/block, coalesced WinT ---------------
__global__ __launch_bounds__(384) void k_inproj(const float* __restrict__ x,
        const float* __restrict__ WinT,
        float* __restrict__ conv_in, float* __restrict__ z_silu)
{
    __shared__ float sx[8*DM];
    int pb  = blockIdx.x * 8;
    int c = threadIdx.x;
    sx[c]       = x[(size_t)pb*DM + c];
    sx[c + 384] = x[(size_t)pb*DM + 384 + c];
    __syncthreads();
    float a0=0,a1=0,a2=0,a3=0,a4=0,a5=0,a6=0,a7=0;
    for (int i = 0; i < DM; ++i){
        float w = WinT[(size_t)i*384 + c];
        a0=fmaf(sx[i],w,a0);        a1=fmaf(sx[DM+i],w,a1);
        a2=fmaf(sx[2*DM+i],w,a2);   a3=fmaf(sx[3*DM+i],w,a3);
        a4=fmaf(sx[4*DM+i],w,a4);   a5=fmaf(sx[5*DM+i],w,a5);
        a6=fmaf(sx[6*DM+i],w,a6);   a7=fmaf(sx[7*DM+i],w,a7);
    }
    if (c < DI){
        conv_in[(size_t)(pb+0)*DI+c]=a0; conv_in[(size_t)(pb+1)*DI+c]=a1;
        conv_in[(size_t)(pb+2)*DI+c]=a2; conv_in[(size_t)(pb+3)*DI+c]=a3;
        conv_in[(size_t)(pb+4)*DI+c]=a4; conv_in[(size_t)(pb+5)*DI+c]=a5;
        conv_in[(size_t)(pb+6)*DI+c]=a6; conv_in[(size_t)(pb+7)*DI+c]=a7;
    } else {
        int d = c - DI;
        z_silu[(size_t)(pb+0)*DI+d]=silu(a0); z_silu[(size_t)(pb+1)*DI+d]=silu(a1);
        z_silu[(size_t)(pb+2)*DI+d]=silu(a2); z_silu[(size_t)(pb+3)*DI+d]=silu(a3);
        z_silu[(size_t)(pb+4)*DI+d]=silu(a4); z_silu[(size_t)(pb+5)*DI+d]=silu(a5);
        z_silu[(size_t)(pb+6)*DI+d]=silu(a6); z_silu[(size_t)(pb+7)*DI+d]=silu(a7);
    }
}

// ---------------- Stage 2: depthwise 3x3 conv + bias + silu ------------------
__global__ __launch_bounds__(256) void k_conv(const float* __restrict__ conv_in,
    const float* __restrict__ cw, const float* __restrict__ cb,
    float* __restrict__ xc)
{
    __shared__ float scw[DI*9];
    int tid = threadIdx.x;
    for (int t = tid; t < DI*9; t += 256) scw[t] = cw[t];
    __syncthreads();
    int idx = blockIdx.x*256 + tid;
    int d = idx % DI;
    int p = (idx / DI) % LL;
    int b = idx / (DI*LL);
    int h = p / WW, w = p % WW;
    float acc = cb[d];
    #pragma unroll
    for (int dy = -1; dy <= 1; ++dy){
        int hy = h + dy; if (hy < 0 || hy >= HH) continue;
        #pragma unroll
        for (int dx = -1; dx <= 1; ++dx){
            int wx = w + dx; if (wx < 0 || wx >= WW) continue;
            acc = fmaf(conv_in[((size_t)b*LL + hy*WW + wx)*DI + d],
                       scw[d*9 + (dy+1)*3 + (dx+1)], acc);
        }
    }
    xc[idx] = silu(acc);
}

static __device__ __forceinline__ float dot4(float4 u, float4 w, float acc){
    acc = fmaf(u.x,w.x,acc); acc = fmaf(u.y,w.y,acc);
    acc = fmaf(u.z,w.z,acc); acc = fmaf(u.w,w.w,acc);
    return acc;
}

// ---------------- Stage 3: x_proj, 2 directions/block, block=320 -------------
// Writes rank-6 dts (delta recomputed on the fly in the scans), B, C.
__global__ __launch_bounds__(320, 5) void k_xproj(const float* __restrict__ xc,
   const float* __restrict__ xpw,
   float* __restrict__ dts, float* __restrict__ Bsb, float* __restrict__ Csb)
{
    __shared__ float su[XP*PAD];          // 25.1 KB
    __shared__ float sxd[2][XP][40];      // 10.2 KB
    int gb = blockIdx.x;
    int bp = gb / (LL/XP); int l0 = (gb % (LL/XP)) * XP;
    int b = bp >> 1, p = bp & 1;
    int kA = p, kB = p + 2;
    int bkA = b*4 + kA, bkB = b*4 + kB;
    int tid = threadIdx.x;

    for (int t = tid; t < XP*48; t += 320){
        int lo = t / 48, i4 = t % 48;
        int px = qmap(kA, l0 + lo);
        float4 u = ((const float4*)(xc + ((size_t)b*LL + px)*DI))[i4];
        *((float4*)&su[lo*PAD + i4*4]) = u;
    }
    __syncthreads();

    for (int q = tid; q < 19*16; q += 320){
        int c2 = q >> 4, lo = q & 15;
        int c0 = 2*c2, c1 = c0 + 1;
        const float4* pA0 = (const float4*)(xpw + ((size_t)kA*NC + c0)*DI);
        const float4* pA1 = (const float4*)(xpw + ((size_t)kA*NC + c1)*DI);
        const float4* pB0 = (const float4*)(xpw + ((size_t)kB*NC + c0)*DI);
        const float4* pB1 = (const float4*)(xpw + ((size_t)kB*NC + c1)*DI);
        const float4* ua = (const float4*)&su[lo*PAD];
        const float4* ub = (const float4*)&su[(lo+16)*PAD];
        float a00=0,a01=0,a10=0,a11=0, e00=0,e01=0,e10=0,e11=0;
        #pragma unroll 4
        for (int i4 = 0; i4 < 48; ++i4){
            float4 u0 = ua[i4], u1 = ub[i4];
            float4 wa0 = pA0[i4], wa1 = pA1[i4];
            float4 wb0 = pB0[i4], wb1 = pB1[i4];
            a00 = dot4(u0,wa0,a00); a01 = dot4(u0,wa1,a01);
            a10 = dot4(u1,wa0,a10); a11 = dot4(u1,wa1,a11);
            e00 = dot4(u0,wb0,e00); e01 = dot4(u0,wb1,e01);
            e10 = dot4(u1,wb0,e10); e11 = dot4(u1,wb1,e11);
        }
        sxd[0][lo][c0] = a00;    sxd[0][lo][c1] = a01;
        sxd[0][lo+16][c0] = a10; sxd[0][lo+16][c1] = a11;
        sxd[1][lo][c0] = e00;    sxd[1][lo][c1] = e01;
        sxd[1][lo+16][c0] = e10; sxd[1][lo+16][c1] = e11;
    }
    __syncthreads();

    for (int t = tid; t < 2*XP*NS; t += 320){
        int o = t / (XP*NS); int r2 = t % (XP*NS);
        int lo = r2 / NS, n = r2 % NS;
        int bkx = o ? bkB : bkA;
        int row = o ? (LL-1-(l0+lo)) : (l0+lo);
        Bsb[((size_t)bkx*LL + row)*NS + n] = sxd[o][lo][RK + n];
        Csb[((size_t)bkx*LL + row)*NS + n] = sxd[o][lo][RK + NS + n];
    }
    for (int t = tid; t < 2*XP*RK; t += 320){
        int o = t / (XP*RK); int r2 = t % (XP*RK);
        int lo = r2 / RK, r = r2 % RK;
        int bkx = o ? bkB : bkA;
        int row = o ? (LL-1-(l0+lo)) : (l0+lo);
        dts[((size_t)bkx*LL + row)*RK + r] = sxd[o][lo][r];
    }
}

#define HS(i, comp) h[i] = fmaf(__expf(dl*An[i]), h[i], dlu*(comp))
#define YS(i, comp) y = fmaf(h[i], (comp), y)

// delta from rank-6 dts: softplus(dtb + sum_r dts[l][r]*dtw[d][r])
static __device__ __forceinline__ float mkdelta(const float* tr, const float* w,
                                                float bb){
    float a = bb;
    #pragma unroll
    for (int r = 0; r < RK; ++r) a = fmaf(tr[r], w[r], a);
    return (a > 20.f) ? a : __logf(1.f + __expf(a));
}

// ---------------- Stage 5 P1: local chunk recurrence, split over n-halves ----
// grid: bk(16) x ch(49) x nh(2) = 1568; block 192; h[8]/thread.
__global__ __launch_bounds__(192, 5) void k_scan1(const float* __restrict__ dts,
    const float* __restrict__ xc, const float* __restrict__ Bsb,
    const float* __restrict__ Alog, const float* __restrict__ dtb,
    const float* __restrict__ dtwT,
    float* __restrict__ hend, float* __restrict__ sumdl)
{
    __shared__ float sB[CHL][8];
    __shared__ float sT[CHL][RK];
    int bid = blockIdx.x;
    int nh = bid & 1;
    int ch = (bid >> 1) % NCH;
    int bk = bid / (2*NCH);
    int b = bk >> 2, k = bk & 3;
    int d = threadIdx.x;
    int l0 = ch*CHL;

    const float* xbase = xc + (size_t)b*LL*DI + d;
    const float* Bb = Bsb + ((size_t)bk*LL + l0)*NS + nh*8;
    const float* Tb = dts + ((size_t)bk*LL + l0)*RK;
    for (int t = d; t < CHL*8; t += 192){
        int l = t >> 3, j = t & 7;
        sB[l][j] = Bb[(size_t)l*NS + j];
    }
    for (int t = d; t < CHL*RK; t += 192) ((float*)sT)[t] = Tb[t];

    float An[8];
    {
        const float* ab = Alog + ((size_t)k*DI + d)*NS + nh*8;
        #pragma unroll
        for (int j = 0; j < 8; ++j) An[j] = -__expf(ab[j]);
    }
    float wdt[RK];
    {
        const float* wp = dtwT + (size_t)k*RK*DI + d;
        #pragma unroll
        for (int r = 0; r < RK; ++r) wdt[r] = wp[(size_t)r*DI];
    }
    float bb = dtb[k*DI + d];
    __syncthreads();

    float h[8];
    #pragma unroll
    for (int j = 0; j < 8; ++j) h[j] = 0.f;
    float S = 0.f;

    float uu0 = xbase[(size_t)qmap(k, l0)*DI];
    float uu1 = xbase[(size_t)qmap(k, l0+1)*DI];
    #pragma unroll 1
    for (int l = 0; l < CHL; ++l){
        float uu = uu0; uu0 = uu1;
        if (l + 2 < CHL) uu1 = xbase[(size_t)qmap(k, l0+l+2)*DI];
        float dl = mkdelta(&sT[l][0], wdt, bb);
        S += dl;
        float dlu = dl * uu;
        const float4* br = (const float4*)&sB[l][0];
        float4 b0 = br[0], b1 = br[1];
        HS(0,b0.x); HS(1,b0.y); HS(2,b0.z); HS(3,b0.w);
        HS(4,b1.x); HS(5,b1.y); HS(6,b1.z); HS(7,b1.w);
    }
    size_t hb = ((size_t)bk*NCH + ch)*NS*DI + (size_t)nh*8*DI + d;
    #pragma unroll
    for (int j = 0; j < 8; ++j) hend[hb + (size_t)j*DI] = h[j];
    if (nh == 0) sumdl[((size_t)bk*NCH + ch)*DI + d] = S;
}

// ---------------- Stage 5 P2: combine chunk states in-place (hend -> H0) -----
__global__ __launch_bounds__(256) void k_scan2(float* __restrict__ hend,
    const float* __restrict__ sumdl, const float* __restrict__ Alog)
{
    int blk = blockIdx.x;
    int bk = blk / NDT, part = blk % NDT;
    int k = bk & 3;
    int tid = threadIdx.x;
    int dsub = tid & 15, n = tid >> 4;
    int d = part*16 + dsub;
    float An = -__expf(Alog[((size_t)k*DI + d)*NS + n]);
    size_t base  = ((size_t)bk*NCH)*NS*DI + (size_t)n*DI + d;
    size_t sbase = (size_t)bk*NCH*DI + d;
    float H = 0.f;
    float he = hend[base], S = sumdl[sbase];
    for (int c = 0; c < NCH; ++c){
        float heN = 0.f, SN = 0.f;
        if (c+1 < NCH){
            heN = hend [base  + (size_t)(c+1)*NS*DI];
            SN  = sumdl[sbase + (size_t)(c+1)*DI];
        }
        hend[base + (size_t)c*NS*DI] = H;
        H  = fmaf(__expf(An*S), H, he);
        he = heN; S = SN;
    }
}

// ---------------- Stage 5 P3: full recurrence from H0, write ys rows ---------
// grid: bk(16) x ch(49) = 784; block 192; h[16]/thread; NO atomics:
// output in scan-position space ys[bk][l][d]; cross-merge moves to k_lnout.
__global__ __launch_bounds__(192, 4) void k_scan3(const float* __restrict__ dts,
    const float* __restrict__ xc, const float* __restrict__ Bsb,
    const float* __restrict__ Csb, const float* __restrict__ Alog,
    const float* __restrict__ dtb, const float* __restrict__ dtwT,
    const float* __restrict__ Dsv, const float* __restrict__ H0,
    float* __restrict__ ys)
{
    __shared__ float sB[CHL][NS], sC[CHL][NS];
    __shared__ float sT[CHL][RK];
    int bid = blockIdx.x;
    int bk = bid / NCH, ch = bid % NCH;
    int b = bk >> 2, k = bk & 3;
    int d = threadIdx.x;
    int l0 = ch*CHL;

    const float* xbase = xc + (size_t)b*LL*DI + d;
    const float* Bb = Bsb + ((size_t)bk*LL + l0)*NS;
    const float* Cb = Csb + ((size_t)bk*LL + l0)*NS;
    const float* Tb = dts + ((size_t)bk*LL + l0)*RK;
    float* ybase = ys + ((size_t)bk*LL + l0)*DI + d;
    for (int t = d; t < CHL*NS; t += 192){
        ((float*)sB)[t] = Bb[t];
        ((float*)sC)[t] = Cb[t];
    }
    for (int t = d; t < CHL*RK; t += 192) ((float*)sT)[t] = Tb[t];

    float An[NS];
    {
        const float* ab = Alog + ((size_t)k*DI + d)*NS;
        #pragma unroll
        for (int n = 0; n < NS; ++n) An[n] = -__expf(ab[n]);
    }
    float wdt[RK];
    {
        const float* wp = dtwT + (size_t)k*RK*DI + d;
        #pragma unroll
        for (int r = 0; r < RK; ++r) wdt[r] = wp[(size_t)r*DI];
    }
    float bb = dtb[k*DI + d];
    float Dv = Dsv[k*DI + d];

    float h[NS];
    size_t hb = ((size_t)bk*NCH + ch)*NS*DI + d;
    #pragma unroll
    for (int n = 0; n < NS; ++n) h[n] = H0[hb + (size_t)n*DI];
    __syncthreads();

    float uu0 = xbase[(size_t)qmap(k, l0)*DI];
    float uu1 = xbase[(size_t)qmap(k, l0+1)*DI];
    #pragma unroll 1
    for (int l = 0; l < CHL; ++l){
        float uu = uu0; uu0 = uu1;
        if (l + 2 < CHL) uu1 = xbase[(size_t)qmap(k, l0+l+2)*DI];
        float dl = mkdelta(&sT[l][0], wdt, bb);
        float dlu = dl * uu;
        const float4* br = (const float4*)&sB[l][0];
        const float4* cr = (const float4*)&sC[l][0];
        float4 b0 = br[0], b1 = br[1], b2 = br[2], b3 = br[3];
        HS(0,b0.x);  HS(1,b0.y);  HS(2,b0.z);  HS(3,b0.w);
        HS(4,b1.x);  HS(5,b1.y);  HS(6,b1.z);  HS(7,b1.w);
        HS(8,b2.x);  HS(9,b2.y);  HS(10,b2.z); HS(11,b2.w);
        HS(12,b3.x); HS(13,b3.y); HS(14,b3.z); HS(15,b3.w);
        float4 c0 = cr[0], c1 = cr[1], c2 = cr[2], c3 = cr[3];
        float y = uu * Dv;
        YS(0,c0.x);  YS(1,c0.y);  YS(2,c0.z);  YS(3,c0.w);
        YS(4,c1.x);  YS(5,c1.y);  YS(6,c1.z);  YS(7,c1.w);
        YS(8,c2.x);  YS(9,c2.y);  YS(10,c2.z); YS(11,c2.w);
        YS(12,c3.x); YS(13,c3.y); YS(14,c3.z); YS(15,c3.w);
        ybase[(size_t)l*DI] = y;              // plain coalesced store
    }
}

// ---------------- Stage 6: gather 4 dirs + LN + z-gate + out_proj ------------
__global__ __launch_bounds__(192) void k_lnout(const float* __restrict__ ys,
    const float* __restrict__ z_silu, const float* __restrict__ lnw,
    const float* __restrict__ lnb, const float* __restrict__ WoutT,
    float* __restrict__ out)
{
    __shared__ float syz[LNPX][DI];
    __shared__ float red_s[LNPX][3], red_q[LNPX][3];
    __shared__ float smu[LNPX], srs[LNPX];
    int pg0 = blockIdx.x * LNPX;
    int b = pg0 / LL, q0 = pg0 % LL;
    int tid = threadIdx.x;
    float wln = lnw[tid], bln = lnb[tid];
    float v[LNPX];
    #pragma unroll
    for (int px = 0; px < LNPX; ++px){
        int q = q0 + px;
        int hh = q / WW, w = q % WW;
        int l1 = w*HH + hh;                 // inverse of transpose scan order
        const float* r0 = ys + (((size_t)(b*4+0)*LL) + q)*DI + tid;
        const float* r1 = ys + (((size_t)(b*4+1)*LL) + l1)*DI + tid;
        const float* r2 = ys + (((size_t)(b*4+2)*LL) + (LL-1-q))*DI + tid;
        const float* r3 = ys + (((size_t)(b*4+3)*LL) + (LL-1-l1))*DI + tid;
        v[px] = (*r0 + *r1) + (*r2 + *r3);  // cross-merge gather
    }
    int wid = tid >> 6, lane = tid & 63;
    #pragma unroll
    for (int px = 0; px < LNPX; ++px){
        float s = v[px], sq = v[px]*v[px];
        #pragma unroll
        for (int m = 32; m >= 1; m >>= 1){ s += __shfl_xor(s,m); sq += __shfl_xor(sq,m); }
        if (lane == 0){ red_s[px][wid] = s; red_q[px][wid] = sq; }
    }
    __syncthreads();
    if (tid < LNPX){
        float ts = red_s[tid][0]+red_s[tid][1]+red_s[tid][2];
        float tq = red_q[tid][0]+red_q[tid][1]+red_q[tid][2];
        float mu = ts*(1.f/DI);
        float var = tq*(1.f/DI) - mu*mu;
        smu[tid] = mu; srs[tid] = rsqrtf(var + 1e-5f);
    }
    __syncthreads();
    #pragma unroll
    for (int px = 0; px < LNPX; ++px){
        float z = z_silu[(size_t)(pg0+px)*DI + tid];
        syz[px][tid] = ((v[px]-smu[px])*srs[px]*wln + bln) * z;
    }
    __syncthreads();
    int g = tid / DM, c = tid % DM;
    float a0=0,a1=0,a2=0,a3=0;
    for (int i = 0; i < DI; ++i){
        float w = WoutT[(size_t)i*DM + c];
        a0 = fmaf(syz[g*4+0][i], w, a0);
        a1 = fmaf(syz[g*4+1][i], w, a1);
        a2 = fmaf(syz[g*4+2][i], w, a2);
        a3 = fmaf(syz[g*4+3][i], w, a3);
    }
    out[(size_t)(pg0+g*4+0)*DM + c] = a0;
    out[(size_t)(pg0+g*4+1)*DM + c] = a1;
    out[(size_t)(pg0+g*4+2)*DM + c] = a2;
    out[(size_t)(pg0+g*4+3)*DM + c] = a3;
}

extern "C" void kernel_launch(void* const* d_in, const int* in_sizes, int n_in,
                              void* d_out, int out_size, void* d_ws, size_t ws_size,
                              hipStream_t stream)
{
    const float* x    = (const float*)d_in[0];
    const float* Win  = (const float*)d_in[1];
    const float* cw   = (const float*)d_in[2];
    const float* cb   = (const float*)d_in[3];
    const float* xpw  = (const float*)d_in[4];
    const float* dtw  = (const float*)d_in[5];
    const float* dtb  = (const float*)d_in[6];
    const float* Alog = (const float*)d_in[7];
    const float* Dsv  = (const float*)d_in[8];
    const float* lnw  = (const float*)d_in[9];
    const float* lnb  = (const float*)d_in[10];
    const float* Wout = (const float*)d_in[11];
    float* out = (float*)d_out;

    float* ws      = (float*)d_ws;
    float* conv_in = ws;                                    // [NPIX,DI] dead after k_conv
    float* z_silu  = conv_in + (size_t)NPIX*DI;             // [NPIX,DI]
    float* xc      = z_silu  + (size_t)NPIX*DI;             // [NPIX,DI] live through P3
    float* ys      = xc      + (size_t)NPIX*DI;             // [16,LL,DI] (old delta slot)
    float* Bsb     = ys      + (size_t)BB*KG*LL*DI;         // [16,LL,NS]
    float* Csb     = Bsb     + (size_t)BB*KG*LL*NS;         // [16,LL,NS]
    float* sumdl   = Csb     + (size_t)BB*KG*LL*NS;         // [16,49,DI]
    float* dts     = sumdl   + (size_t)BB*KG*NCH*DI;        // [16,LL,6]
    float* WinT    = dts     + (size_t)BB*KG*LL*RK;         // [96,384]
    float* WoutT   = WinT    + (size_t)DM*2*DI;             // [192,96]
    float* dtwT    = WoutT   + (size_t)DI*DM;               // [4,6,192]
    float* hend    = conv_in;  // alias: [16,49,16,192] == NPIX*DI; H0 in-place after P2

    hipLaunchKernelGGL(k_prep,   dim3((384*DM + DI*DM + KG*RK*DI + 255)/256), dim3(256), 0, stream,
                       Win, Wout, dtw, WinT, WoutT, dtwT);
    hipLaunchKernelGGL(k_inproj, dim3(NPIX/8), dim3(384), 0, stream, x, WinT, conv_in, z_silu);
    hipLaunchKernelGGL(k_conv,   dim3((NPIX*DI)/256), dim3(256), 0, stream, conv_in, cw, cb, xc);
    hipLaunchKernelGGL(k_xproj,  dim3(BB*2*(LL/XP)), dim3(320), 0, stream, xc, xpw, dts, Bsb, Csb);
    hipLaunchKernelGGL(k_scan1, dim3(BB*KG*NCH*2), dim3(192), 0, stream,
                       dts, xc, Bsb, Alog, dtb, dtwT, hend, sumdl);
    hipLaunchKernelGGL(k_scan2, dim3(BB*KG*NDT), dim3(256), 0, stream,
                       hend, sumdl, Alog);
    hipLaunchKernelGGL(k_scan3, dim3(BB*KG*NCH), dim3(192), 0, stream,
                       dts, xc, Bsb, Csb, Alog, dtb, dtwT, Dsv, hend, ys);
    hipLaunchKernelGGL(k_lnout,  dim3(NPIX/LNPX), dim3(192), 0, stream, ys, z_silu, lnw, lnb, WoutT, out);
}